// Round 7
// baseline (258.837 us; speedup 1.0000x reference)
//
#include <hip/hip_runtime.h>
#include <cstddef>

#define H 256
#define NHEADS 8
#define HD 32

typedef __attribute__((ext_vector_type(8))) short bf16x8;
typedef __attribute__((ext_vector_type(4))) float f32x4;

__device__ __forceinline__ float bf2f(unsigned short s) {
    unsigned u = ((unsigned)s) << 16; return __builtin_bit_cast(float, u);
}
__device__ __forceinline__ float bfe2f(short s) {
    unsigned u = ((unsigned)(unsigned short)s) << 16; return __builtin_bit_cast(float, u);
}
__device__ __forceinline__ unsigned short f2bf(float x) {
    unsigned u = __builtin_bit_cast(unsigned, x);
    u += 0x7fffu + ((u >> 16) & 1u);           // round-to-nearest-even
    return (unsigned short)(u >> 16);
}
__device__ __forceinline__ void gl_lds16(const void* g, void* l) {
    __builtin_amdgcn_global_load_lds(
        (const __attribute__((address_space(1))) void*)g,
        (__attribute__((address_space(3))) void*)l, 16, 0, 0);
}

// ---------------------------------------------------------------------------
// PRE: merged {prepass | cvtW | scan+zero} in one launch.
// ---------------------------------------------------------------------------
#define PS 2696
__global__ __launch_bounds__(256) void pre_kernel(
    const float* __restrict__ src, const float* __restrict__ dst,
    const float* __restrict__ W1, const float* __restrict__ W2,
    const int* __restrict__ slen, const int* __restrict__ dlen,
    unsigned short* __restrict__ KT, unsigned short* __restrict__ VT2,
    unsigned short* __restrict__ QT,
    unsigned short* __restrict__ W1p, unsigned short* __restrict__ W2bf,
    int* __restrict__ soff, int* __restrict__ doff,
    float* __restrict__ stats, int N, int B)
{
    __shared__ unsigned short pl[8 * PS];
    const int t = threadIdx.x;
    const int bid = blockIdx.x;
    const int prepB = N >> 5;                    // (N/64)*2

    if (bid < prepB) {
        // ---- prepass ----
        const int rb = (bid >> 1) * 64;
        const int isrc = (bid & 1) == 0;
        const float* __restrict__ in = isrc ? src : dst;
        unsigned short* __restrict__ T = isrc ? KT : QT;
        #pragma unroll
        for (int i = 0; i < 16; ++i) {
            const int idx = t + i * 256;         // 4096 float4s
            const int row = idx >> 6, f4 = idx & 63;
            const float4 v = ((const float4*)in)[(size_t)(rb + row) * 64 + f4];
            const int f0 = f4 * 4, h0 = f0 & 7, d = f0 >> 3;
            pl[(h0 + 0) * PS + row * 42 + d] = f2bf(v.x);
            pl[(h0 + 1) * PS + row * 42 + d] = f2bf(v.y);
            pl[(h0 + 2) * PS + row * 42 + d] = f2bf(v.z);
            pl[(h0 + 3) * PS + row * 42 + d] = f2bf(v.w);
        }
        __syncthreads();
        #pragma unroll
        for (int i = 0; i < 8; ++i) {
            const int idx = t + i * 256;         // 2048 16B chunks
            const int h = idx >> 8, rem = idx & 255, row = rem >> 2, c = rem & 3;
            const bf16x8 val = *(const bf16x8*)&pl[h * PS + row * 42 + c * 8];
            *(bf16x8*)&T[(size_t)(h * N + rb + row) * 32 + c * 8] = val;
        }
        if (isrc) {
            #pragma unroll
            for (int i = 0; i < 8; ++i) {
                const int idx = t + i * 256;     // 8 planes x 32 d x 8 n-chunks
                const int h = idx >> 8, rem = idx & 255, d = rem >> 3, nc = rem & 7;
                bf16x8 v8;
                #pragma unroll
                for (int j = 0; j < 8; ++j)
                    v8[j] = (short)pl[h * PS + (nc * 8 + j) * 42 + d];
                *(bf16x8*)&VT2[(size_t)(h * 32 + d) * N + rb + nc * 8] = v8;
            }
        }
    } else if (bid < prepB + 768) {
        // ---- weights cvt: W1 K-permuted (kp = half*256 + h*32 + d), W2 plain
        const int idx = (bid - prepB) * 256 + t;
        if (idx < 131072) {
            const int kp = idx & 511, c = idx >> 9;
            const int half = kp >> 8, r = kp & 255, hh = r >> 5, d = r & 31;
            W1p[(size_t)c * 512 + kp] = f2bf(W1[(size_t)c * 512 + half * 256 + d * 8 + hh]);
        } else {
            const int i2 = idx - 131072;
            W2bf[i2] = f2bf(W2[i2]);
        }
    } else {
        // ---- stats zero + lens exclusive scan (one wave, shfl-scan) ----
        stats[t] = 0.f; stats[t + 256] = 0.f; stats[t + 512] = 0.f; stats[t + 768] = 0.f;
        if (t < 64) {
            int sv[8], dv[8];
            int sl = 0, dl = 0;
            #pragma unroll
            for (int j = 0; j < 8; ++j) {
                const int g = t * 8 + j;
                sv[j] = sl; dv[j] = dl;
                sl += (g < B) ? slen[g] : 0;
                dl += (g < B) ? dlen[g] : 0;
            }
            int sx = sl, dx = dl;
            #pragma unroll
            for (int o = 1; o < 64; o <<= 1) {
                const int sy = __shfl_up(sx, o);
                const int dy = __shfl_up(dx, o);
                if (t >= o) { sx += sy; dx += dy; }
            }
            const int sbase = sx - sl, dbase = dx - dl;
            #pragma unroll
            for (int j = 0; j < 8; ++j) {
                const int g = t * 8 + j;
                if (g < B) { soff[g] = sbase + sv[j]; doff[g] = dbase + dv[j]; }
            }
        }
    }
}

// ---------------------------------------------------------------------------
// K2: MFMA attention (one wave per (graph, head)); Q double-buffered.
// ---------------------------------------------------------------------------
template<int LS>
__device__ __forceinline__ void attn_body(
    const unsigned short* __restrict__ KT, const unsigned short* __restrict__ QT,
    const unsigned short* __restrict__ VT2, unsigned short* __restrict__ OT,
    unsigned short* __restrict__ Ps, int N, int so, int df, int Ld, int h, int lane)
{
    constexpr int MT = LS / 16, CH = LS / 32;
    const int lr = lane & 15, lq = lane >> 4;
    const float iscale = 0.17677669529663687f;  // 1/sqrt(32)

    bf16x8 kf[MT];
    #pragma unroll
    for (int mt = 0; mt < MT; ++mt)
        kf[mt] = *(const bf16x8*)&KT[(size_t)(h * N + so + mt * 16 + lr) * 32 + lq * 8];
    bf16x8 vf[CH][2];
    #pragma unroll
    for (int c = 0; c < CH; ++c)
        #pragma unroll
        for (int dt = 0; dt < 2; ++dt)
            vf[c][dt] = *(const bf16x8*)&VT2[(size_t)(h * 32 + dt * 16 + lr) * N + so + c * 32 + lq * 8];

    const int NT = Ld >> 4;
    bf16x8 qf = *(const bf16x8*)&QT[(size_t)(h * N + df + lr) * 32 + lq * 8];
    for (int nt = 0; nt < NT; ++nt) {
        bf16x8 qn = qf;
        if (nt + 1 < NT)
            qn = *(const bf16x8*)&QT[(size_t)(h * N + df + (nt + 1) * 16 + lr) * 32 + lq * 8];
        f32x4 s[MT];
        #pragma unroll
        for (int mt = 0; mt < MT; ++mt) {
            f32x4 z = {0.f, 0.f, 0.f, 0.f};
            s[mt] = __builtin_amdgcn_mfma_f32_16x16x32_bf16(kf[mt], qf, z, 0, 0, 0);
        }
        float mx = -INFINITY;
        #pragma unroll
        for (int mt = 0; mt < MT; ++mt)
            mx = fmaxf(mx, fmaxf(fmaxf(s[mt][0], s[mt][1]), fmaxf(s[mt][2], s[mt][3])));
        mx = fmaxf(mx, __shfl_xor(mx, 16));
        mx = fmaxf(mx, __shfl_xor(mx, 32));
        const float mxi = mx * iscale;
        float sum = 0.f;
        #pragma unroll
        for (int mt = 0; mt < MT; ++mt) {
            #pragma unroll
            for (int r = 0; r < 4; ++r) {
                const float e = __expf(s[mt][r] * iscale - mxi);
                s[mt][r] = e; sum += e;
            }
        }
        sum += __shfl_xor(sum, 16);
        sum += __shfl_xor(sum, 32);
        const float rinv = 1.f / sum;
        #pragma unroll
        for (int mt = 0; mt < MT; ++mt) {
            uint2 p;
            p.x = ((unsigned)f2bf(s[mt][0])) | (((unsigned)f2bf(s[mt][1])) << 16);
            p.y = ((unsigned)f2bf(s[mt][2])) | (((unsigned)f2bf(s[mt][3])) << 16);
            *(uint2*)&Ps[lr * 136 + mt * 16 + lq * 4] = p;
        }
        __asm__ volatile("" ::: "memory");
        __builtin_amdgcn_wave_barrier();
        f32x4 o0 = {0.f, 0.f, 0.f, 0.f}, o1 = {0.f, 0.f, 0.f, 0.f};
        #pragma unroll
        for (int c = 0; c < CH; ++c) {
            const bf16x8 pa = *(const bf16x8*)&Ps[lr * 136 + c * 32 + lq * 8];
            o0 = __builtin_amdgcn_mfma_f32_16x16x32_bf16(pa, vf[c][0], o0, 0, 0, 0);
            o1 = __builtin_amdgcn_mfma_f32_16x16x32_bf16(pa, vf[c][1], o1, 0, 0, 0);
        }
        __asm__ volatile("" ::: "memory");
        __builtin_amdgcn_wave_barrier();
        #pragma unroll
        for (int r = 0; r < 4; ++r) {
            const float rv = __shfl(rinv, lq * 4 + r);
            const int row = df + nt * 16 + lq * 4 + r;
            OT[(size_t)(h * N + row) * 32 + lr]      = f2bf(o0[r] * rv);
            OT[(size_t)(h * N + row) * 32 + 16 + lr] = f2bf(o1[r] * rv);
        }
        qf = qn;
    }
}

// LPT remap: heavy (l=128) graphs dispatch first, light (l=32) pack the tail.
__global__ __launch_bounds__(256) void attn_mfma(
    const unsigned short* __restrict__ KT, const unsigned short* __restrict__ QT,
    const unsigned short* __restrict__ VT2, unsigned short* __restrict__ OT,
    const int* __restrict__ soff, const int* __restrict__ doff,
    const int* __restrict__ slen, const int* __restrict__ dlen, int N)
{
    __shared__ unsigned short Ps[4][16 * 136];
    const int i = blockIdx.x >> 1, half = blockIdx.x & 1;
    const int grp = i >> 7, j = i & 127;
    const int b = 4 * j + (3 - grp);             // bijective over [0,512)
    const int w = threadIdx.x >> 6, lane = threadIdx.x & 63;
    const int h = half * 4 + w;
    const int Ls = slen[b], Ld = dlen[b], so = soff[b], df = doff[b];
    switch (Ls) {
        case 32:  attn_body<32> (KT, QT, VT2, OT, Ps[w], N, so, df, Ld, h, lane); break;
        case 64:  attn_body<64> (KT, QT, VT2, OT, Ps[w], N, so, df, Ld, h, lane); break;
        case 96:  attn_body<96> (KT, QT, VT2, OT, Ps[w], N, so, df, Ld, h, lane); break;
        default:  attn_body<128>(KT, QT, VT2, OT, Ps[w], N, so, df, Ld, h, lane); break;
    }
}

// ---------------------------------------------------------------------------
// K3: GEMM1. 128x128 tile, BK=64 (8 K-steps of 32 MFMA; was 16 steps of 16):
// halves the number of staging round-trips per block -- R0-R5 bracketed the
// bottleneck to per-step latency stall, so fewer+fatter steps win. LDS = 64KB
// (2buf x (16KB A + 16KB B)), ~2 blocks/CU (matches current effective
// residency). XCD swizzle (T1): col-pair blocks (cb=0,1) of the same row
// panel land on the SAME XCD (bid%8 = XCD), so the 2nd A fetch is an L2 hit
// (~200cy vs ~900cy) -- targets the latency bound directly.
// Accumulation order (ks ascending) identical to R6 -> bitwise-same output.
// ---------------------------------------------------------------------------
__global__ __launch_bounds__(256) void gemm1_mfma(
    const unsigned short* __restrict__ QT, const unsigned short* __restrict__ OT,
    const unsigned short* __restrict__ W, const float* __restrict__ bias,
    unsigned short* __restrict__ out, float* __restrict__ sum, float* __restrict__ sq,
    int N)
{
    __shared__ unsigned short Abuf[2][16 * 512];  // [bi][khalf s][8 subs][512]
    __shared__ unsigned short Bbuf[2][16 * 512];
    const int tid = threadIdx.x;
    const int w = tid >> 6, lane = tid & 63;
    // XCD swizzle decode: bid = 8*(2*(y/8)+cb) + (y%8)
    const int bid = blockIdx.x;
    const int xcd = bid & 7, q = bid >> 3;
    const int cb = q & 1, y = (q >> 1) * 8 + xcd;
    const int rowBase = y * 128, colBase = cb * 128;
    const int lr = lane & 15, lq = lane >> 4;
    const int wm = w >> 1, wn = w & 1;

    f32x4 acc[4][4];
    #pragma unroll
    for (int i = 0; i < 4; ++i)
        #pragma unroll
        for (int j = 0; j < 4; ++j) { f32x4 z = {0.f, 0.f, 0.f, 0.f}; acc[i][j] = z; }

    // step p in [0,8): covers ks = 2p, 2p+1 (QT heads for p<4, OT for p>=4).
    auto stage = [&](int p, int bi) {
        const unsigned short* __restrict__ Ap = (p < 4) ? QT : OT;
        #pragma unroll
        for (int s = 0; s < 2; ++s) {
            const int ks = 2 * p + s;
            const int hh = ks & 7;
            #pragma unroll
            for (int t2 = 0; t2 < 2; ++t2) {
                const int sub = 2 * w + t2;
                gl_lds16(Ap + (size_t)(hh * N + rowBase + sub * 16 + lr) * 32 + lq * 8,
                         &Abuf[bi][s * 4096 + sub * 512]);
                gl_lds16(W + (size_t)(colBase + sub * 16 + lr) * 512 + ks * 32 + lq * 8,
                         &Bbuf[bi][s * 4096 + sub * 512]);
            }
        }
    };
    auto compute = [&](int bi) {
        #pragma unroll
        for (int s = 0; s < 2; ++s) {
            bf16x8 af[4], bfr[4];
            #pragma unroll
            for (int i = 0; i < 4; ++i)
                af[i] = *(const bf16x8*)&Abuf[bi][s * 4096 + (wm * 4 + i) * 512 + lane * 8];
            #pragma unroll
            for (int j = 0; j < 4; ++j)
                bfr[j] = *(const bf16x8*)&Bbuf[bi][s * 4096 + (wn * 4 + j) * 512 + lane * 8];
            #pragma unroll
            for (int i = 0; i < 4; ++i)
                #pragma unroll
                for (int j = 0; j < 4; ++j)
                    acc[i][j] = __builtin_amdgcn_mfma_f32_16x16x32_bf16(af[i], bfr[j], acc[i][j], 0, 0, 0);
        }
    };

    stage(0, 0);
    __syncthreads();
    for (int p = 0; p < 8; p += 2) {
        stage(p + 1, 1);
        compute(0);
        __syncthreads();
        if (p + 2 < 8) stage(p + 2, 0);
        compute(1);
        __syncthreads();
    }

    const int col0 = colBase + wn * 64;
    #pragma unroll
    for (int j = 0; j < 4; ++j) {
        const int col = col0 + j * 16 + lr;
        const float bv = bias[col];
        float cs = 0.f, cq = 0.f;
        #pragma unroll
        for (int i = 0; i < 4; ++i) {
            const int row0 = rowBase + wm * 64 + i * 16 + lq * 4;
            #pragma unroll
            for (int r = 0; r < 4; ++r) {
                const float v = acc[i][j][r] + bv;
                cs += v; cq += v * v;
                out[(size_t)(row0 + r) * 256 + col] = f2bf(v);
            }
        }
        cs += __shfl_xor(cs, 16); cs += __shfl_xor(cs, 32);
        cq += __shfl_xor(cq, 16); cq += __shfl_xor(cq, 32);
        if (lq == 0) { atomicAdd(&sum[col], cs); atomicAdd(&sq[col], cq); }
    }
}

// ---------------------------------------------------------------------------
// K5: GEMM2 with FUSED bn1+relu on the A path. R6 structure + XCD swizzle.
// ---------------------------------------------------------------------------
__global__ __launch_bounds__(256) void gemm2_fused(
    const unsigned short* __restrict__ y1,
    const unsigned short* __restrict__ W, const float* __restrict__ bias,
    const float* __restrict__ sum1, const float* __restrict__ sq1,
    const float* __restrict__ gamma1, const float* __restrict__ beta1,
    unsigned short* __restrict__ out, float* __restrict__ sum, float* __restrict__ sq,
    float invN)
{
    __shared__ unsigned short Abuf[2][8 * 512];
    __shared__ unsigned short Bbuf[2][8 * 512];
    __shared__ float scs[256], shs[256];
    const int tid = threadIdx.x;
    const int w = tid >> 6, lane = tid & 63;
    const int bid = blockIdx.x;
    const int xcd = bid & 7, q = bid >> 3;
    const int cb = q & 1, y = (q >> 1) * 8 + xcd;
    const int rowBase = y * 128, colBase = cb * 128;
    const int lr = lane & 15, lq = lane >> 4;
    const int wm = w >> 1, wn = w & 1;

    {   // per-column bn1 scale/shift (identical arithmetic to R6)
        const float mean = sum1[tid] * invN;
        const float var  = sq1[tid] * invN - mean * mean;
        const float rstd = rsqrtf(var + 1e-5f);
        const float sc = gamma1[tid] * rstd;
        scs[tid] = sc;
        shs[tid] = beta1[tid] - mean * sc;
    }

    f32x4 acc[4][4];
    #pragma unroll
    for (int i = 0; i < 4; ++i)
        #pragma unroll
        for (int j = 0; j < 4; ++j) { f32x4 z = {0.f, 0.f, 0.f, 0.f}; acc[i][j] = z; }

    bf16x8 rawA[2];
    auto loadA = [&](int ks) {
        #pragma unroll
        for (int s = 0; s < 2; ++s) {
            const int sub = 2 * w + s;
            rawA[s] = *(const bf16x8*)&y1[(size_t)(rowBase + sub * 16 + lr) * 256 + ks * 32 + lq * 8];
        }
    };
    auto writeA = [&](int ks, int bi) {
        const int k0 = ks * 32 + lq * 8;
        #pragma unroll
        for (int s = 0; s < 2; ++s) {
            const int sub = 2 * w + s;
            bf16x8 o;
            #pragma unroll
            for (int j = 0; j < 8; ++j)
                o[j] = (short)f2bf(fmaxf(bfe2f(rawA[s][j]) * scs[k0 + j] + shs[k0 + j], 0.f));
            *(bf16x8*)&Abuf[bi][sub * 512 + lane * 8] = o;
        }
    };
    auto stageB = [&](int ks, int bi) {
        #pragma unroll
        for (int s = 0; s < 2; ++s) {
            const int sub = 2 * w + s;
            gl_lds16(W + (size_t)(colBase + sub * 16 + lr) * 256 + ks * 32 + lq * 8,
                     &Bbuf[bi][sub * 512]);
        }
    };
    auto compute = [&](int bi) {
        bf16x8 af[4], bfr[4];
        #pragma unroll
        for (int i = 0; i < 4; ++i) af[i] = *(const bf16x8*)&Abuf[bi][(wm * 4 + i) * 512 + lane * 8];
        #pragma unroll
        for (int j = 0; j < 4; ++j) bfr[j] = *(const bf16x8*)&Bbuf[bi][(wn * 4 + j) * 512 + lane * 8];
        #pragma unroll
        for (int i = 0; i < 4; ++i)
            #pragma unroll
            for (int j = 0; j < 4; ++j)
                acc[i][j] = __builtin_amdgcn_mfma_f32_16x16x32_bf16(af[i], bfr[j], acc[i][j], 0, 0, 0);
    };

    __syncthreads();                     // scs/shs visible
    loadA(0); stageB(0, 0); writeA(0, 0);
    __syncthreads();                     // Abuf[0] written, Bbuf[0] landed
    for (int ks = 0; ks < 8; ++ks) {
        const int cur = ks & 1;
        if (ks + 1 < 8) { loadA(ks + 1); stageB(ks + 1, cur ^ 1); }
        compute(cur);
        if (ks + 1 < 8) writeA(ks + 1, cur ^ 1);
        __syncthreads();
    }

    const int col0 = colBase + wn * 64;
    #pragma unroll
    for (int j = 0; j < 4; ++j) {
        const int col = col0 + j * 16 + lr;
        const float bv = bias[col];
        float cs = 0.f, cq = 0.f;
        #pragma unroll
        for (int i = 0; i < 4; ++i) {
            const int row0 = rowBase + wm * 64 + i * 16 + lq * 4;
            #pragma unroll
            for (int r = 0; r < 4; ++r) {
                const float v = acc[i][j][r] + bv;
                cs += v; cq += v * v;
                out[(size_t)(row0 + r) * 256 + col] = f2bf(v);
            }
        }
        cs += __shfl_xor(cs, 16); cs += __shfl_xor(cs, 32);
        cq += __shfl_xor(cq, 16); cq += __shfl_xor(cq, 32);
        if (lq == 0) { atomicAdd(&sum[col], cs); atomicAdd(&sq[col], cq); }
    }
}

// ---------------------------------------------------------------------------
// epilogue: out = dst + bn2(y2bf), finalize inlined. 8 elems/thread.
// ---------------------------------------------------------------------------
__global__ __launch_bounds__(256) void epilogue_kernel(
    const float* __restrict__ dst, const unsigned short* __restrict__ y2,
    const float* __restrict__ sum, const float* __restrict__ sq,
    const float* __restrict__ gamma, const float* __restrict__ beta,
    float* __restrict__ out, int n8, float invN)
{
    const int i = blockIdx.x * 256 + threadIdx.x;
    if (i >= n8) return;
    const int j0 = (i & 31) * 8;
    const bf16x8 yv = ((const bf16x8*)y2)[i];
    const float4 d0 = ((const float4*)dst)[2 * i];
    const float4 d1 = ((const float4*)dst)[2 * i + 1];
    float o[8];
    const float dv[8] = {d0.x, d0.y, d0.z, d0.w, d1.x, d1.y, d1.z, d1.w};
    #pragma unroll
    for (int j = 0; j < 8; ++j) {
        const float mean = sum[j0 + j] * invN;
        const float var  = sq[j0 + j] * invN - mean * mean;
        const float rstd = rsqrtf(var + 1e-5f);
        const float sc = gamma[j0 + j] * rstd;
        const float sh = beta[j0 + j] - mean * sc;
        o[j] = dv[j] + bfe2f(yv[j]) * sc + sh;
    }
    float4 o0, o1;
    o0.x = o[0]; o0.y = o[1]; o0.z = o[2]; o0.w = o[3];
    o1.x = o[4]; o1.y = o[5]; o1.z = o[6]; o1.w = o[7];
    ((float4*)out)[2 * i]     = o0;
    ((float4*)out)[2 * i + 1] = o1;
}

// ---------------------------------------------------------------------------
extern "C" void kernel_launch(void* const* d_in, const int* in_sizes, int n_in,
                              void* d_out, int out_size, void* d_ws, size_t ws_size,
                              hipStream_t stream)
{
    const float* src_h  = (const float*)d_in[0];
    const float* dst_h  = (const float*)d_in[1];
    const int*   slen   = (const int*)d_in[2];
    const int*   dlen   = (const int*)d_in[3];
    const float* W1     = (const float*)d_in[4];
    const float* b1     = (const float*)d_in[5];
    const float* gamma1 = (const float*)d_in[6];
    const float* beta1  = (const float*)d_in[7];
    const float* W2     = (const float*)d_in[8];
    const float* b2     = (const float*)d_in[9];
    const float* gamma2 = (const float*)d_in[10];
    const float* beta2  = (const float*)d_in[11];
    float* out = (float*)d_out;

    const int N = in_sizes[1] / H;     // 40960
    const int B = in_sizes[2];         // 512

    // ---- workspace layout (bytes) ----
    char* base = (char*)d_ws;
    int*   soff   = (int*)(base + 0);            // 2KB
    int*   doff   = (int*)(base + 2048);         // 2KB
    float* stats  = (float*)(base + 4096);       // 4KB: sum1, sq1, sum2, sq2
    unsigned short* W1p  = (unsigned short*)(base + 16384);            // 256KB
    unsigned short* W2bf = (unsigned short*)(base + 16384 + 262144);   // 128KB
    const size_t S = (size_t)N * H * sizeof(unsigned short);           // 21 MB
    char* big = base + (1 << 20);
    unsigned short* KT  = (unsigned short*)(big);
    unsigned short* VT2 = (unsigned short*)(big + S);
    unsigned short* QT  = (unsigned short*)(big + 2 * S);
    unsigned short* OT  = (unsigned short*)(big + 3 * S);
    unsigned short* y1bf = KT;    // reuse after attention
    unsigned short* y2bf = QT;    // reuse after gemm1 (gemm2 reads y1bf only)

    const float invN = 1.0f / (float)N;

    const int prepB = N >> 5;                       // 1280
    pre_kernel<<<prepB + 768 + 1, 256, 0, stream>>>(
        src_h, dst_h, W1, W2, slen, dlen,
        KT, VT2, QT, W1p, W2bf, soff, doff, stats, N, B);

    attn_mfma<<<B * 2, 256, 0, stream>>>(KT, QT, VT2, OT, soff, doff, slen, dlen, N);

    // 640 blocks = 320 row panels x 2 col blocks, XCD-paired
    gemm1_mfma<<<640, 256, 0, stream>>>(QT, OT, W1p, b1, y1bf, stats + 0, stats + 256, N);

    gemm2_fused<<<640, 256, 0, stream>>>(
        y1bf, W2bf, b2, stats + 0, stats + 256, gamma1, beta1,
        y2bf, stats + 512, stats + 768, invN);

    const int n8 = N * H / 8;
    epilogue_kernel<<<(n8 + 255) / 256, 256, 0, stream>>>(
        dst_h, y2bf, stats + 512, stats + 768, gamma2, beta2, out, n8, invN);
}

// Round 8
// 252.535 us; speedup vs baseline: 1.0250x; 1.0250x over previous
//
#include <hip/hip_runtime.h>
#include <cstddef>

#define H 256
#define NHEADS 8
#define HD 32

typedef __attribute__((ext_vector_type(8))) short bf16x8;
typedef __attribute__((ext_vector_type(4))) float f32x4;

__device__ __forceinline__ float bf2f(unsigned short s) {
    unsigned u = ((unsigned)s) << 16; return __builtin_bit_cast(float, u);
}
__device__ __forceinline__ float bfe2f(short s) {
    unsigned u = ((unsigned)(unsigned short)s) << 16; return __builtin_bit_cast(float, u);
}
__device__ __forceinline__ unsigned short f2bf(float x) {
    unsigned u = __builtin_bit_cast(unsigned, x);
    u += 0x7fffu + ((u >> 16) & 1u);           // round-to-nearest-even
    return (unsigned short)(u >> 16);
}
__device__ __forceinline__ void gl_lds16(const void* g, void* l) {
    __builtin_amdgcn_global_load_lds(
        (const __attribute__((address_space(1))) void*)g,
        (__attribute__((address_space(3))) void*)l, 16, 0, 0);
}

// ---------------------------------------------------------------------------
// PRE: merged {prepass | cvtW | scan+zero} in one launch.
// Prepass now 32 rows/block (was 64): LDS 43.5KB -> 21.6KB per block lifts
// residency 3 -> 7 blocks/CU (pre was latency-bound at Occupancy 23%), and
// 2x blocks shorten the serial load->sync->store chain.
// PS = 32*42+8 = 1352 shorts = 676 dwords == 4 mod 32 (2-way plane aliasing).
// ---------------------------------------------------------------------------
#define PS 1352
__global__ __launch_bounds__(256) void pre_kernel(
    const float* __restrict__ src, const float* __restrict__ dst,
    const float* __restrict__ W1, const float* __restrict__ W2,
    const int* __restrict__ slen, const int* __restrict__ dlen,
    unsigned short* __restrict__ KT, unsigned short* __restrict__ VT2,
    unsigned short* __restrict__ QT,
    unsigned short* __restrict__ W1p, unsigned short* __restrict__ W2bf,
    int* __restrict__ soff, int* __restrict__ doff,
    float* __restrict__ stats, int N, int B)
{
    __shared__ unsigned short pl[8 * PS];
    const int t = threadIdx.x;
    const int bid = blockIdx.x;
    const int prepB = N >> 4;                    // (N/32)*2

    if (bid < prepB) {
        // ---- prepass: 32 rows ----
        const int rb = (bid >> 1) * 32;
        const int isrc = (bid & 1) == 0;
        const float* __restrict__ in = isrc ? src : dst;
        unsigned short* __restrict__ T = isrc ? KT : QT;
        #pragma unroll
        for (int i = 0; i < 8; ++i) {
            const int idx = t + i * 256;         // 2048 float4s (32 rows x 64)
            const int row = idx >> 6, f4 = idx & 63;
            const float4 v = ((const float4*)in)[(size_t)(rb + row) * 64 + f4];
            const int f0 = f4 * 4, h0 = f0 & 7, d = f0 >> 3;
            pl[(h0 + 0) * PS + row * 42 + d] = f2bf(v.x);
            pl[(h0 + 1) * PS + row * 42 + d] = f2bf(v.y);
            pl[(h0 + 2) * PS + row * 42 + d] = f2bf(v.z);
            pl[(h0 + 3) * PS + row * 42 + d] = f2bf(v.w);
        }
        __syncthreads();
        #pragma unroll
        for (int i = 0; i < 4; ++i) {
            const int idx = t + i * 256;         // 1024 16B chunks (8h x 32r x 4c)
            const int h = idx >> 7, rem = idx & 127, row = rem >> 2, c = rem & 3;
            const bf16x8 val = *(const bf16x8*)&pl[h * PS + row * 42 + c * 8];
            *(bf16x8*)&T[(size_t)(h * N + rb + row) * 32 + c * 8] = val;
        }
        if (isrc) {
            #pragma unroll
            for (int i = 0; i < 4; ++i) {
                const int idx = t + i * 256;     // 8 planes x 32 d x 4 n-chunks
                const int h = idx >> 7, rem = idx & 127, d = rem >> 2, nc = rem & 3;
                bf16x8 v8;
                #pragma unroll
                for (int j = 0; j < 8; ++j)
                    v8[j] = (short)pl[h * PS + (nc * 8 + j) * 42 + d];
                *(bf16x8*)&VT2[(size_t)(h * 32 + d) * N + rb + nc * 8] = v8;
            }
        }
    } else if (bid < prepB + 768) {
        // ---- weights cvt: W1 K-permuted (kp = half*256 + h*32 + d), W2 plain
        const int idx = (bid - prepB) * 256 + t;
        if (idx < 131072) {
            const int kp = idx & 511, c = idx >> 9;
            const int half = kp >> 8, r = kp & 255, hh = r >> 5, d = r & 31;
            W1p[(size_t)c * 512 + kp] = f2bf(W1[(size_t)c * 512 + half * 256 + d * 8 + hh]);
        } else {
            const int i2 = idx - 131072;
            W2bf[i2] = f2bf(W2[i2]);
        }
    } else {
        // ---- stats zero + lens exclusive scan (one wave, shfl-scan) ----
        stats[t] = 0.f; stats[t + 256] = 0.f; stats[t + 512] = 0.f; stats[t + 768] = 0.f;
        if (t < 64) {
            int sv[8], dv[8];
            int sl = 0, dl = 0;
            #pragma unroll
            for (int j = 0; j < 8; ++j) {
                const int g = t * 8 + j;
                sv[j] = sl; dv[j] = dl;
                sl += (g < B) ? slen[g] : 0;
                dl += (g < B) ? dlen[g] : 0;
            }
            int sx = sl, dx = dl;
            #pragma unroll
            for (int o = 1; o < 64; o <<= 1) {
                const int sy = __shfl_up(sx, o);
                const int dy = __shfl_up(dx, o);
                if (t >= o) { sx += sy; dx += dy; }
            }
            const int sbase = sx - sl, dbase = dx - dl;
            #pragma unroll
            for (int j = 0; j < 8; ++j) {
                const int g = t * 8 + j;
                if (g < B) { soff[g] = sbase + sv[j]; doff[g] = dbase + dv[j]; }
            }
        }
    }
}

// ---------------------------------------------------------------------------
// K2: MFMA attention (one wave per (graph, head)); Q double-buffered.
// ---------------------------------------------------------------------------
template<int LS>
__device__ __forceinline__ void attn_body(
    const unsigned short* __restrict__ KT, const unsigned short* __restrict__ QT,
    const unsigned short* __restrict__ VT2, unsigned short* __restrict__ OT,
    unsigned short* __restrict__ Ps, int N, int so, int df, int Ld, int h, int lane)
{
    constexpr int MT = LS / 16, CH = LS / 32;
    const int lr = lane & 15, lq = lane >> 4;
    const float iscale = 0.17677669529663687f;  // 1/sqrt(32)

    bf16x8 kf[MT];
    #pragma unroll
    for (int mt = 0; mt < MT; ++mt)
        kf[mt] = *(const bf16x8*)&KT[(size_t)(h * N + so + mt * 16 + lr) * 32 + lq * 8];
    bf16x8 vf[CH][2];
    #pragma unroll
    for (int c = 0; c < CH; ++c)
        #pragma unroll
        for (int dt = 0; dt < 2; ++dt)
            vf[c][dt] = *(const bf16x8*)&VT2[(size_t)(h * 32 + dt * 16 + lr) * N + so + c * 32 + lq * 8];

    const int NT = Ld >> 4;
    bf16x8 qf = *(const bf16x8*)&QT[(size_t)(h * N + df + lr) * 32 + lq * 8];
    for (int nt = 0; nt < NT; ++nt) {
        bf16x8 qn = qf;
        if (nt + 1 < NT)
            qn = *(const bf16x8*)&QT[(size_t)(h * N + df + (nt + 1) * 16 + lr) * 32 + lq * 8];
        f32x4 s[MT];
        #pragma unroll
        for (int mt = 0; mt < MT; ++mt) {
            f32x4 z = {0.f, 0.f, 0.f, 0.f};
            s[mt] = __builtin_amdgcn_mfma_f32_16x16x32_bf16(kf[mt], qf, z, 0, 0, 0);
        }
        float mx = -INFINITY;
        #pragma unroll
        for (int mt = 0; mt < MT; ++mt)
            mx = fmaxf(mx, fmaxf(fmaxf(s[mt][0], s[mt][1]), fmaxf(s[mt][2], s[mt][3])));
        mx = fmaxf(mx, __shfl_xor(mx, 16));
        mx = fmaxf(mx, __shfl_xor(mx, 32));
        const float mxi = mx * iscale;
        float sum = 0.f;
        #pragma unroll
        for (int mt = 0; mt < MT; ++mt) {
            #pragma unroll
            for (int r = 0; r < 4; ++r) {
                const float e = __expf(s[mt][r] * iscale - mxi);
                s[mt][r] = e; sum += e;
            }
        }
        sum += __shfl_xor(sum, 16);
        sum += __shfl_xor(sum, 32);
        const float rinv = 1.f / sum;
        #pragma unroll
        for (int mt = 0; mt < MT; ++mt) {
            uint2 p;
            p.x = ((unsigned)f2bf(s[mt][0])) | (((unsigned)f2bf(s[mt][1])) << 16);
            p.y = ((unsigned)f2bf(s[mt][2])) | (((unsigned)f2bf(s[mt][3])) << 16);
            *(uint2*)&Ps[lr * 136 + mt * 16 + lq * 4] = p;
        }
        __asm__ volatile("" ::: "memory");
        __builtin_amdgcn_wave_barrier();
        f32x4 o0 = {0.f, 0.f, 0.f, 0.f}, o1 = {0.f, 0.f, 0.f, 0.f};
        #pragma unroll
        for (int c = 0; c < CH; ++c) {
            const bf16x8 pa = *(const bf16x8*)&Ps[lr * 136 + c * 32 + lq * 8];
            o0 = __builtin_amdgcn_mfma_f32_16x16x32_bf16(pa, vf[c][0], o0, 0, 0, 0);
            o1 = __builtin_amdgcn_mfma_f32_16x16x32_bf16(pa, vf[c][1], o1, 0, 0, 0);
        }
        __asm__ volatile("" ::: "memory");
        __builtin_amdgcn_wave_barrier();
        #pragma unroll
        for (int r = 0; r < 4; ++r) {
            const float rv = __shfl(rinv, lq * 4 + r);
            const int row = df + nt * 16 + lq * 4 + r;
            OT[(size_t)(h * N + row) * 32 + lr]      = f2bf(o0[r] * rv);
            OT[(size_t)(h * N + row) * 32 + 16 + lr] = f2bf(o1[r] * rv);
        }
        qf = qn;
    }
}

// LPT remap: heavy (l=128) graphs dispatch first, light (l=32) pack the tail.
__global__ __launch_bounds__(256) void attn_mfma(
    const unsigned short* __restrict__ KT, const unsigned short* __restrict__ QT,
    const unsigned short* __restrict__ VT2, unsigned short* __restrict__ OT,
    const int* __restrict__ soff, const int* __restrict__ doff,
    const int* __restrict__ slen, const int* __restrict__ dlen, int N)
{
    __shared__ unsigned short Ps[4][16 * 136];
    const int i = blockIdx.x >> 1, half = blockIdx.x & 1;
    const int grp = i >> 7, j = i & 127;
    const int b = 4 * j + (3 - grp);             // bijective over [0,512)
    const int w = threadIdx.x >> 6, lane = threadIdx.x & 63;
    const int h = half * 4 + w;
    const int Ls = slen[b], Ld = dlen[b], so = soff[b], df = doff[b];
    switch (Ls) {
        case 32:  attn_body<32> (KT, QT, VT2, OT, Ps[w], N, so, df, Ld, h, lane); break;
        case 64:  attn_body<64> (KT, QT, VT2, OT, Ps[w], N, so, df, Ld, h, lane); break;
        case 96:  attn_body<96> (KT, QT, VT2, OT, Ps[w], N, so, df, Ld, h, lane); break;
        default:  attn_body<128>(KT, QT, VT2, OT, Ps[w], N, so, df, Ld, h, lane); break;
    }
}

// ---------------------------------------------------------------------------
// K3: GEMM1. R6's proven structure (128x128, BK=32, depth-1 dbuf, 32KB LDS)
// + XCD swizzle ONLY (isolated): both col-blocks of a row panel share an XCD
// (bid%8 = y%8), so the 2nd A-panel fetch is an L2 hit. R7 proved FETCH
// halves (42->22MB); R7's time regression was BK=64's occupancy loss (m132),
// now reverted. Accumulation order identical -> bitwise-same output.
// ---------------------------------------------------------------------------
__global__ __launch_bounds__(256) void gemm1_mfma(
    const unsigned short* __restrict__ QT, const unsigned short* __restrict__ OT,
    const unsigned short* __restrict__ W, const float* __restrict__ bias,
    unsigned short* __restrict__ out, float* __restrict__ sum, float* __restrict__ sq,
    int N)
{
    __shared__ unsigned short Abuf[2][8 * 512];
    __shared__ unsigned short Bbuf[2][8 * 512];
    const int tid = threadIdx.x;
    const int w = tid >> 6, lane = tid & 63;
    // XCD swizzle decode: bid = 8*(2*(y/8)+cb) + (y%8)
    const int bid = blockIdx.x;
    const int xcd = bid & 7, q = bid >> 3;
    const int cb = q & 1, y = (q >> 1) * 8 + xcd;
    const int rowBase = y * 128, colBase = cb * 128;
    const int lr = lane & 15, lq = lane >> 4;
    const int wm = w >> 1, wn = w & 1;

    f32x4 acc[4][4];
    #pragma unroll
    for (int i = 0; i < 4; ++i)
        #pragma unroll
        for (int j = 0; j < 4; ++j) { f32x4 z = {0.f, 0.f, 0.f, 0.f}; acc[i][j] = z; }

    // K-step ks in [0,16): phase = ks>>3 (QT then OT), head hh = ks&7.
    auto stage = [&](int ks, int bi) {
        const unsigned short* __restrict__ Ap = (ks < 8) ? QT : OT;
        const int hh = ks & 7;
        #pragma unroll
        for (int s = 0; s < 2; ++s) {
            const int sub = 2 * w + s;
            gl_lds16(Ap + (size_t)(hh * N + rowBase + sub * 16 + lr) * 32 + lq * 8,
                     &Abuf[bi][sub * 512]);
            gl_lds16(W + (size_t)(colBase + sub * 16 + lr) * 512 + ks * 32 + lq * 8,
                     &Bbuf[bi][sub * 512]);
        }
    };
    auto compute = [&](int bi) {
        bf16x8 af[4], bfr[4];
        #pragma unroll
        for (int i = 0; i < 4; ++i) af[i] = *(const bf16x8*)&Abuf[bi][(wm * 4 + i) * 512 + lane * 8];
        #pragma unroll
        for (int j = 0; j < 4; ++j) bfr[j] = *(const bf16x8*)&Bbuf[bi][(wn * 4 + j) * 512 + lane * 8];
        #pragma unroll
        for (int i = 0; i < 4; ++i)
            #pragma unroll
            for (int j = 0; j < 4; ++j)
                acc[i][j] = __builtin_amdgcn_mfma_f32_16x16x32_bf16(af[i], bfr[j], acc[i][j], 0, 0, 0);
    };

    stage(0, 0);
    __syncthreads();
    for (int ks = 0; ks < 16; ks += 2) {
        stage(ks + 1, 1);
        compute(0);
        __syncthreads();
        if (ks + 2 < 16) stage(ks + 2, 0);
        compute(1);
        __syncthreads();
    }

    const int col0 = colBase + wn * 64;
    #pragma unroll
    for (int j = 0; j < 4; ++j) {
        const int col = col0 + j * 16 + lr;
        const float bv = bias[col];
        float cs = 0.f, cq = 0.f;
        #pragma unroll
        for (int i = 0; i < 4; ++i) {
            const int row0 = rowBase + wm * 64 + i * 16 + lq * 4;
            #pragma unroll
            for (int r = 0; r < 4; ++r) {
                const float v = acc[i][j][r] + bv;
                cs += v; cq += v * v;
                out[(size_t)(row0 + r) * 256 + col] = f2bf(v);
            }
        }
        cs += __shfl_xor(cs, 16); cs += __shfl_xor(cs, 32);
        cq += __shfl_xor(cq, 16); cq += __shfl_xor(cq, 32);
        if (lq == 0) { atomicAdd(&sum[col], cs); atomicAdd(&sq[col], cq); }
    }
}

// ---------------------------------------------------------------------------
// K5: GEMM2 with FUSED bn1+relu on the A path (R6 exact; no swizzle).
// ---------------------------------------------------------------------------
__global__ __launch_bounds__(256) void gemm2_fused(
    const unsigned short* __restrict__ y1,
    const unsigned short* __restrict__ W, const float* __restrict__ bias,
    const float* __restrict__ sum1, const float* __restrict__ sq1,
    const float* __restrict__ gamma1, const float* __restrict__ beta1,
    unsigned short* __restrict__ out, float* __restrict__ sum, float* __restrict__ sq,
    float invN)
{
    __shared__ unsigned short Abuf[2][8 * 512];
    __shared__ unsigned short Bbuf[2][8 * 512];
    __shared__ float scs[256], shs[256];
    const int tid = threadIdx.x;
    const int w = tid >> 6, lane = tid & 63;
    const int rowBase = blockIdx.y * 128, colBase = blockIdx.x * 128;
    const int lr = lane & 15, lq = lane >> 4;
    const int wm = w >> 1, wn = w & 1;

    {   // per-column bn1 scale/shift (identical arithmetic to bnrelu)
        const float mean = sum1[tid] * invN;
        const float var  = sq1[tid] * invN - mean * mean;
        const float rstd = rsqrtf(var + 1e-5f);
        const float sc = gamma1[tid] * rstd;
        scs[tid] = sc;
        shs[tid] = beta1[tid] - mean * sc;
    }

    f32x4 acc[4][4];
    #pragma unroll
    for (int i = 0; i < 4; ++i)
        #pragma unroll
        for (int j = 0; j < 4; ++j) { f32x4 z = {0.f, 0.f, 0.f, 0.f}; acc[i][j] = z; }

    bf16x8 rawA[2];
    auto loadA = [&](int ks) {
        #pragma unroll
        for (int s = 0; s < 2; ++s) {
            const int sub = 2 * w + s;
            rawA[s] = *(const bf16x8*)&y1[(size_t)(rowBase + sub * 16 + lr) * 256 + ks * 32 + lq * 8];
        }
    };
    auto writeA = [&](int ks, int bi) {
        const int k0 = ks * 32 + lq * 8;
        #pragma unroll
        for (int s = 0; s < 2; ++s) {
            const int sub = 2 * w + s;
            bf16x8 o;
            #pragma unroll
            for (int j = 0; j < 8; ++j)
                o[j] = (short)f2bf(fmaxf(bfe2f(rawA[s][j]) * scs[k0 + j] + shs[k0 + j], 0.f));
            *(bf16x8*)&Abuf[bi][sub * 512 + lane * 8] = o;
        }
    };
    auto stageB = [&](int ks, int bi) {
        #pragma unroll
        for (int s = 0; s < 2; ++s) {
            const int sub = 2 * w + s;
            gl_lds16(W + (size_t)(colBase + sub * 16 + lr) * 256 + ks * 32 + lq * 8,
                     &Bbuf[bi][sub * 512]);
        }
    };
    auto compute = [&](int bi) {
        bf16x8 af[4], bfr[4];
        #pragma unroll
        for (int i = 0; i < 4; ++i) af[i] = *(const bf16x8*)&Abuf[bi][(wm * 4 + i) * 512 + lane * 8];
        #pragma unroll
        for (int j = 0; j < 4; ++j) bfr[j] = *(const bf16x8*)&Bbuf[bi][(wn * 4 + j) * 512 + lane * 8];
        #pragma unroll
        for (int i = 0; i < 4; ++i)
            #pragma unroll
            for (int j = 0; j < 4; ++j)
                acc[i][j] = __builtin_amdgcn_mfma_f32_16x16x32_bf16(af[i], bfr[j], acc[i][j], 0, 0, 0);
    };

    __syncthreads();                     // scs/shs visible
    loadA(0); stageB(0, 0); writeA(0, 0);
    __syncthreads();                     // Abuf[0] written, Bbuf[0] landed
    for (int ks = 0; ks < 8; ++ks) {
        const int cur = ks & 1;
        if (ks + 1 < 8) { loadA(ks + 1); stageB(ks + 1, cur ^ 1); }
        compute(cur);
        if (ks + 1 < 8) writeA(ks + 1, cur ^ 1);
        __syncthreads();
    }

    const int col0 = colBase + wn * 64;
    #pragma unroll
    for (int j = 0; j < 4; ++j) {
        const int col = col0 + j * 16 + lr;
        const float bv = bias[col];
        float cs = 0.f, cq = 0.f;
        #pragma unroll
        for (int i = 0; i < 4; ++i) {
            const int row0 = rowBase + wm * 64 + i * 16 + lq * 4;
            #pragma unroll
            for (int r = 0; r < 4; ++r) {
                const float v = acc[i][j][r] + bv;
                cs += v; cq += v * v;
                out[(size_t)(row0 + r) * 256 + col] = f2bf(v);
            }
        }
        cs += __shfl_xor(cs, 16); cs += __shfl_xor(cs, 32);
        cq += __shfl_xor(cq, 16); cq += __shfl_xor(cq, 32);
        if (lq == 0) { atomicAdd(&sum[col], cs); atomicAdd(&sq[col], cq); }
    }
}

// ---------------------------------------------------------------------------
// epilogue: out = dst + bn2(y2bf), finalize inlined. 8 elems/thread.
// ---------------------------------------------------------------------------
__global__ __launch_bounds__(256) void epilogue_kernel(
    const float* __restrict__ dst, const unsigned short* __restrict__ y2,
    const float* __restrict__ sum, const float* __restrict__ sq,
    const float* __restrict__ gamma, const float* __restrict__ beta,
    float* __restrict__ out, int n8, float invN)
{
    const int i = blockIdx.x * 256 + threadIdx.x;
    if (i >= n8) return;
    const int j0 = (i & 31) * 8;
    const bf16x8 yv = ((const bf16x8*)y2)[i];
    const float4 d0 = ((const float4*)dst)[2 * i];
    const float4 d1 = ((const float4*)dst)[2 * i + 1];
    float o[8];
    const float dv[8] = {d0.x, d0.y, d0.z, d0.w, d1.x, d1.y, d1.z, d1.w};
    #pragma unroll
    for (int j = 0; j < 8; ++j) {
        const float mean = sum[j0 + j] * invN;
        const float var  = sq[j0 + j] * invN - mean * mean;
        const float rstd = rsqrtf(var + 1e-5f);
        const float sc = gamma[j0 + j] * rstd;
        const float sh = beta[j0 + j] - mean * sc;
        o[j] = dv[j] + bfe2f(yv[j]) * sc + sh;
    }
    float4 o0, o1;
    o0.x = o[0]; o0.y = o[1]; o0.z = o[2]; o0.w = o[3];
    o1.x = o[4]; o1.y = o[5]; o1.z = o[6]; o1.w = o[7];
    ((float4*)out)[2 * i]     = o0;
    ((float4*)out)[2 * i + 1] = o1;
}

// ---------------------------------------------------------------------------
extern "C" void kernel_launch(void* const* d_in, const int* in_sizes, int n_in,
                              void* d_out, int out_size, void* d_ws, size_t ws_size,
                              hipStream_t stream)
{
    const float* src_h  = (const float*)d_in[0];
    const float* dst_h  = (const float*)d_in[1];
    const int*   slen   = (const int*)d_in[2];
    const int*   dlen   = (const int*)d_in[3];
    const float* W1     = (const float*)d_in[4];
    const float* b1     = (const float*)d_in[5];
    const float* gamma1 = (const float*)d_in[6];
    const float* beta1  = (const float*)d_in[7];
    const float* W2     = (const float*)d_in[8];
    const float* b2     = (const float*)d_in[9];
    const float* gamma2 = (const float*)d_in[10];
    const float* beta2  = (const float*)d_in[11];
    float* out = (float*)d_out;

    const int N = in_sizes[1] / H;     // 40960
    const int B = in_sizes[2];         // 512

    // ---- workspace layout (bytes) ----
    char* base = (char*)d_ws;
    int*   soff   = (int*)(base + 0);            // 2KB
    int*   doff   = (int*)(base + 2048);         // 2KB
    float* stats  = (float*)(base + 4096);       // 4KB: sum1, sq1, sum2, sq2
    unsigned short* W1p  = (unsigned short*)(base + 16384);            // 256KB
    unsigned short* W2bf = (unsigned short*)(base + 16384 + 262144);   // 128KB
    const size_t S = (size_t)N * H * sizeof(unsigned short);           // 21 MB
    char* big = base + (1 << 20);
    unsigned short* KT  = (unsigned short*)(big);
    unsigned short* VT2 = (unsigned short*)(big + S);
    unsigned short* QT  = (unsigned short*)(big + 2 * S);
    unsigned short* OT  = (unsigned short*)(big + 3 * S);
    unsigned short* y1bf = KT;    // reuse after attention
    unsigned short* y2bf = QT;    // reuse after gemm1 (gemm2 reads y1bf only)

    const float invN = 1.0f / (float)N;

    const int prepB = N >> 4;                       // 2560
    pre_kernel<<<prepB + 768 + 1, 256, 0, stream>>>(
        src_h, dst_h, W1, W2, slen, dlen,
        KT, VT2, QT, W1p, W2bf, soff, doff, stats, N, B);

    attn_mfma<<<B * 2, 256, 0, stream>>>(KT, QT, VT2, OT, soff, doff, slen, dlen, N);

    // 640 blocks = 320 row panels x 2 col blocks, XCD-paired
    gemm1_mfma<<<640, 256, 0, stream>>>(QT, OT, W1p, b1, y1bf, stats + 0, stats + 256, N);

    dim3 ggrid(H / 128, N / 128);     // (2, 320)
    gemm2_fused<<<ggrid, 256, 0, stream>>>(
        y1bf, W2bf, b2, stats + 0, stats + 256, gamma1, beta1,
        y2bf, stats + 512, stats + 768, invN);

    const int n8 = N * H / 8;
    epilogue_kernel<<<(n8 + 255) / 256, 256, 0, stream>>>(
        dst_h, y2bf, stats + 512, stats + 768, gamma2, beta2, out, n8, invN);
}

// Round 9
// 250.921 us; speedup vs baseline: 1.0316x; 1.0064x over previous
//
#include <hip/hip_runtime.h>
#include <cstddef>

#define H 256
#define NHEADS 8
#define HD 32

typedef __attribute__((ext_vector_type(8))) short bf16x8;
typedef __attribute__((ext_vector_type(4))) float f32x4;

__device__ __forceinline__ float bf2f(unsigned short s) {
    unsigned u = ((unsigned)s) << 16; return __builtin_bit_cast(float, u);
}
__device__ __forceinline__ float bfe2f(short s) {
    unsigned u = ((unsigned)(unsigned short)s) << 16; return __builtin_bit_cast(float, u);
}
__device__ __forceinline__ unsigned short f2bf(float x) {
    unsigned u = __builtin_bit_cast(unsigned, x);
    u += 0x7fffu + ((u >> 16) & 1u);           // round-to-nearest-even
    return (unsigned short)(u >> 16);
}
__device__ __forceinline__ void gl_lds16(const void* g, void* l) {
    __builtin_amdgcn_global_load_lds(
        (const __attribute__((address_space(1))) void*)g,
        (__attribute__((address_space(3))) void*)l, 16, 0, 0);
}

// ---------------------------------------------------------------------------
// PRE: merged {prepass | cvtW | scan+zero} in one launch. 64-row prepass
// blocks (R6 config, 41.4us known-good; R8's 32-row split regressed to 45).
// Row stride 42 shorts: VT2 gather nc-stride 336 shorts == 8 mod 32 dwords
// -> 4-way; plane stride PS=2696 == 4 mod 32 dwords -> 2-way (free).
// ---------------------------------------------------------------------------
#define PS 2696
__global__ __launch_bounds__(256) void pre_kernel(
    const float* __restrict__ src, const float* __restrict__ dst,
    const float* __restrict__ W1, const float* __restrict__ W2,
    const int* __restrict__ slen, const int* __restrict__ dlen,
    unsigned short* __restrict__ KT, unsigned short* __restrict__ VT2,
    unsigned short* __restrict__ QT,
    unsigned short* __restrict__ W1p, unsigned short* __restrict__ W2bf,
    int* __restrict__ soff, int* __restrict__ doff,
    float* __restrict__ stats, int N, int B)
{
    __shared__ unsigned short pl[8 * PS];
    const int t = threadIdx.x;
    const int bid = blockIdx.x;
    const int prepB = N >> 5;                    // (N/64)*2

    if (bid < prepB) {
        // ---- prepass ----
        const int rb = (bid >> 1) * 64;
        const int isrc = (bid & 1) == 0;
        const float* __restrict__ in = isrc ? src : dst;
        unsigned short* __restrict__ T = isrc ? KT : QT;
        #pragma unroll
        for (int i = 0; i < 16; ++i) {
            const int idx = t + i * 256;         // 4096 float4s
            const int row = idx >> 6, f4 = idx & 63;
            const float4 v = ((const float4*)in)[(size_t)(rb + row) * 64 + f4];
            const int f0 = f4 * 4, h0 = f0 & 7, d = f0 >> 3;
            pl[(h0 + 0) * PS + row * 42 + d] = f2bf(v.x);
            pl[(h0 + 1) * PS + row * 42 + d] = f2bf(v.y);
            pl[(h0 + 2) * PS + row * 42 + d] = f2bf(v.z);
            pl[(h0 + 3) * PS + row * 42 + d] = f2bf(v.w);
        }
        __syncthreads();
        #pragma unroll
        for (int i = 0; i < 8; ++i) {
            const int idx = t + i * 256;         // 2048 16B chunks
            const int h = idx >> 8, rem = idx & 255, row = rem >> 2, c = rem & 3;
            const bf16x8 val = *(const bf16x8*)&pl[h * PS + row * 42 + c * 8];
            *(bf16x8*)&T[(size_t)(h * N + rb + row) * 32 + c * 8] = val;
        }
        if (isrc) {
            #pragma unroll
            for (int i = 0; i < 8; ++i) {
                const int idx = t + i * 256;     // 8 planes x 32 d x 8 n-chunks
                const int h = idx >> 8, rem = idx & 255, d = rem >> 3, nc = rem & 7;
                bf16x8 v8;
                #pragma unroll
                for (int j = 0; j < 8; ++j)
                    v8[j] = (short)pl[h * PS + (nc * 8 + j) * 42 + d];
                *(bf16x8*)&VT2[(size_t)(h * 32 + d) * N + rb + nc * 8] = v8;
            }
        }
    } else if (bid < prepB + 768) {
        // ---- weights cvt: W1 K-permuted (kp = half*256 + h*32 + d), W2 plain
        const int idx = (bid - prepB) * 256 + t;
        if (idx < 131072) {
            const int kp = idx & 511, c = idx >> 9;
            const int half = kp >> 8, r = kp & 255, hh = r >> 5, d = r & 31;
            W1p[(size_t)c * 512 + kp] = f2bf(W1[(size_t)c * 512 + half * 256 + d * 8 + hh]);
        } else {
            const int i2 = idx - 131072;
            W2bf[i2] = f2bf(W2[i2]);
        }
    } else {
        // ---- stats zero + lens exclusive scan (one wave, shfl-scan) ----
        stats[t] = 0.f; stats[t + 256] = 0.f; stats[t + 512] = 0.f; stats[t + 768] = 0.f;
        if (t < 64) {
            int sv[8], dv[8];
            int sl = 0, dl = 0;
            #pragma unroll
            for (int j = 0; j < 8; ++j) {
                const int g = t * 8 + j;
                sv[j] = sl; dv[j] = dl;
                sl += (g < B) ? slen[g] : 0;
                dl += (g < B) ? dlen[g] : 0;
            }
            int sx = sl, dx = dl;
            #pragma unroll
            for (int o = 1; o < 64; o <<= 1) {
                const int sy = __shfl_up(sx, o);
                const int dy = __shfl_up(dx, o);
                if (t >= o) { sx += sy; dx += dy; }
            }
            const int sbase = sx - sl, dbase = dx - dl;
            #pragma unroll
            for (int j = 0; j < 8; ++j) {
                const int g = t * 8 + j;
                if (g < B) { soff[g] = sbase + sv[j]; doff[g] = dbase + dv[j]; }
            }
        }
    }
}

// ---------------------------------------------------------------------------
// K2: MFMA attention (one wave per (graph, head)); Q double-buffered.
// T5 setprio around MFMA clusters: independent-wave regime (m191 confirmed
// +4-7% on exactly this structure) -- MFMA-entering wave preempts waves
// sitting in the softmax VALU chain. Scheduling-only, no numeric effect.
// ---------------------------------------------------------------------------
template<int LS>
__device__ __forceinline__ void attn_body(
    const unsigned short* __restrict__ KT, const unsigned short* __restrict__ QT,
    const unsigned short* __restrict__ VT2, unsigned short* __restrict__ OT,
    unsigned short* __restrict__ Ps, int N, int so, int df, int Ld, int h, int lane)
{
    constexpr int MT = LS / 16, CH = LS / 32;
    const int lr = lane & 15, lq = lane >> 4;
    const float iscale = 0.17677669529663687f;  // 1/sqrt(32)

    bf16x8 kf[MT];
    #pragma unroll
    for (int mt = 0; mt < MT; ++mt)
        kf[mt] = *(const bf16x8*)&KT[(size_t)(h * N + so + mt * 16 + lr) * 32 + lq * 8];
    bf16x8 vf[CH][2];
    #pragma unroll
    for (int c = 0; c < CH; ++c)
        #pragma unroll
        for (int dt = 0; dt < 2; ++dt)
            vf[c][dt] = *(const bf16x8*)&VT2[(size_t)(h * 32 + dt * 16 + lr) * N + so + c * 32 + lq * 8];

    const int NT = Ld >> 4;
    bf16x8 qf = *(const bf16x8*)&QT[(size_t)(h * N + df + lr) * 32 + lq * 8];
    for (int nt = 0; nt < NT; ++nt) {
        bf16x8 qn = qf;
        if (nt + 1 < NT)
            qn = *(const bf16x8*)&QT[(size_t)(h * N + df + (nt + 1) * 16 + lr) * 32 + lq * 8];
        f32x4 s[MT];
        __builtin_amdgcn_s_setprio(1);
        #pragma unroll
        for (int mt = 0; mt < MT; ++mt) {
            f32x4 z = {0.f, 0.f, 0.f, 0.f};
            s[mt] = __builtin_amdgcn_mfma_f32_16x16x32_bf16(kf[mt], qf, z, 0, 0, 0);
        }
        __builtin_amdgcn_s_setprio(0);
        float mx = -INFINITY;
        #pragma unroll
        for (int mt = 0; mt < MT; ++mt)
            mx = fmaxf(mx, fmaxf(fmaxf(s[mt][0], s[mt][1]), fmaxf(s[mt][2], s[mt][3])));
        mx = fmaxf(mx, __shfl_xor(mx, 16));
        mx = fmaxf(mx, __shfl_xor(mx, 32));
        const float mxi = mx * iscale;
        float sum = 0.f;
        #pragma unroll
        for (int mt = 0; mt < MT; ++mt) {
            #pragma unroll
            for (int r = 0; r < 4; ++r) {
                const float e = __expf(s[mt][r] * iscale - mxi);
                s[mt][r] = e; sum += e;
            }
        }
        sum += __shfl_xor(sum, 16);
        sum += __shfl_xor(sum, 32);
        const float rinv = 1.f / sum;
        #pragma unroll
        for (int mt = 0; mt < MT; ++mt) {
            uint2 p;
            p.x = ((unsigned)f2bf(s[mt][0])) | (((unsigned)f2bf(s[mt][1])) << 16);
            p.y = ((unsigned)f2bf(s[mt][2])) | (((unsigned)f2bf(s[mt][3])) << 16);
            *(uint2*)&Ps[lr * 136 + mt * 16 + lq * 4] = p;
        }
        __asm__ volatile("" ::: "memory");
        __builtin_amdgcn_wave_barrier();
        f32x4 o0 = {0.f, 0.f, 0.f, 0.f}, o1 = {0.f, 0.f, 0.f, 0.f};
        __builtin_amdgcn_s_setprio(1);
        #pragma unroll
        for (int c = 0; c < CH; ++c) {
            const bf16x8 pa = *(const bf16x8*)&Ps[lr * 136 + c * 32 + lq * 8];
            o0 = __builtin_amdgcn_mfma_f32_16x16x32_bf16(pa, vf[c][0], o0, 0, 0, 0);
            o1 = __builtin_amdgcn_mfma_f32_16x16x32_bf16(pa, vf[c][1], o1, 0, 0, 0);
        }
        __builtin_amdgcn_s_setprio(0);
        __asm__ volatile("" ::: "memory");
        __builtin_amdgcn_wave_barrier();
        #pragma unroll
        for (int r = 0; r < 4; ++r) {
            const float rv = __shfl(rinv, lq * 4 + r);
            const int row = df + nt * 16 + lq * 4 + r;
            OT[(size_t)(h * N + row) * 32 + lr]      = f2bf(o0[r] * rv);
            OT[(size_t)(h * N + row) * 32 + 16 + lr] = f2bf(o1[r] * rv);
        }
        qf = qn;
    }
}

// LPT remap: heavy (l=128) graphs dispatch first, light (l=32) pack the tail.
__global__ __launch_bounds__(256) void attn_mfma(
    const unsigned short* __restrict__ KT, const unsigned short* __restrict__ QT,
    const unsigned short* __restrict__ VT2, unsigned short* __restrict__ OT,
    const int* __restrict__ soff, const int* __restrict__ doff,
    const int* __restrict__ slen, const int* __restrict__ dlen, int N)
{
    __shared__ unsigned short Ps[4][16 * 136];
    const int i = blockIdx.x >> 1, half = blockIdx.x & 1;
    const int grp = i >> 7, j = i & 127;
    const int b = 4 * j + (3 - grp);             // bijective over [0,512)
    const int w = threadIdx.x >> 6, lane = threadIdx.x & 63;
    const int h = half * 4 + w;
    const int Ls = slen[b], Ld = dlen[b], so = soff[b], df = doff[b];
    switch (Ls) {
        case 32:  attn_body<32> (KT, QT, VT2, OT, Ps[w], N, so, df, Ld, h, lane); break;
        case 64:  attn_body<64> (KT, QT, VT2, OT, Ps[w], N, so, df, Ld, h, lane); break;
        case 96:  attn_body<96> (KT, QT, VT2, OT, Ps[w], N, so, df, Ld, h, lane); break;
        default:  attn_body<128>(KT, QT, VT2, OT, Ps[w], N, so, df, Ld, h, lane); break;
    }
}

// ---------------------------------------------------------------------------
// K3: GEMM1 (R8 exact: 128x128, BK=32, depth-1 dbuf, XCD swizzle).
// ---------------------------------------------------------------------------
__global__ __launch_bounds__(256) void gemm1_mfma(
    const unsigned short* __restrict__ QT, const unsigned short* __restrict__ OT,
    const unsigned short* __restrict__ W, const float* __restrict__ bias,
    unsigned short* __restrict__ out, float* __restrict__ sum, float* __restrict__ sq,
    int N)
{
    __shared__ unsigned short Abuf[2][8 * 512];
    __shared__ unsigned short Bbuf[2][8 * 512];
    const int tid = threadIdx.x;
    const int w = tid >> 6, lane = tid & 63;
    // XCD swizzle decode: bid = 8*(2*(y/8)+cb) + (y%8)
    const int bid = blockIdx.x;
    const int xcd = bid & 7, q = bid >> 3;
    const int cb = q & 1, y = (q >> 1) * 8 + xcd;
    const int rowBase = y * 128, colBase = cb * 128;
    const int lr = lane & 15, lq = lane >> 4;
    const int wm = w >> 1, wn = w & 1;

    f32x4 acc[4][4];
    #pragma unroll
    for (int i = 0; i < 4; ++i)
        #pragma unroll
        for (int j = 0; j < 4; ++j) { f32x4 z = {0.f, 0.f, 0.f, 0.f}; acc[i][j] = z; }

    // K-step ks in [0,16): phase = ks>>3 (QT then OT), head hh = ks&7.
    auto stage = [&](int ks, int bi) {
        const unsigned short* __restrict__ Ap = (ks < 8) ? QT : OT;
        const int hh = ks & 7;
        #pragma unroll
        for (int s = 0; s < 2; ++s) {
            const int sub = 2 * w + s;
            gl_lds16(Ap + (size_t)(hh * N + rowBase + sub * 16 + lr) * 32 + lq * 8,
                     &Abuf[bi][sub * 512]);
            gl_lds16(W + (size_t)(colBase + sub * 16 + lr) * 512 + ks * 32 + lq * 8,
                     &Bbuf[bi][sub * 512]);
        }
    };
    auto compute = [&](int bi) {
        bf16x8 af[4], bfr[4];
        #pragma unroll
        for (int i = 0; i < 4; ++i) af[i] = *(const bf16x8*)&Abuf[bi][(wm * 4 + i) * 512 + lane * 8];
        #pragma unroll
        for (int j = 0; j < 4; ++j) bfr[j] = *(const bf16x8*)&Bbuf[bi][(wn * 4 + j) * 512 + lane * 8];
        #pragma unroll
        for (int i = 0; i < 4; ++i)
            #pragma unroll
            for (int j = 0; j < 4; ++j)
                acc[i][j] = __builtin_amdgcn_mfma_f32_16x16x32_bf16(af[i], bfr[j], acc[i][j], 0, 0, 0);
    };

    stage(0, 0);
    __syncthreads();
    for (int ks = 0; ks < 16; ks += 2) {
        stage(ks + 1, 1);
        compute(0);
        __syncthreads();
        if (ks + 2 < 16) stage(ks + 2, 0);
        compute(1);
        __syncthreads();
    }

    const int col0 = colBase + wn * 64;
    #pragma unroll
    for (int j = 0; j < 4; ++j) {
        const int col = col0 + j * 16 + lr;
        const float bv = bias[col];
        float cs = 0.f, cq = 0.f;
        #pragma unroll
        for (int i = 0; i < 4; ++i) {
            const int row0 = rowBase + wm * 64 + i * 16 + lq * 4;
            #pragma unroll
            for (int r = 0; r < 4; ++r) {
                const float v = acc[i][j][r] + bv;
                cs += v; cq += v * v;
                out[(size_t)(row0 + r) * 256 + col] = f2bf(v);
            }
        }
        cs += __shfl_xor(cs, 16); cs += __shfl_xor(cs, 32);
        cq += __shfl_xor(cq, 16); cq += __shfl_xor(cq, 32);
        if (lq == 0) { atomicAdd(&sum[col], cs); atomicAdd(&sq[col], cq); }
    }
}

// ---------------------------------------------------------------------------
// K5: GEMM2 with FUSED bn1+relu on the A path + XCD swizzle (same decode as
// gemm1: both col-blocks of a row panel share an XCD -> 2nd y1-panel read is
// an L2 hit, the mechanism R7 proved on gemm1).
// ---------------------------------------------------------------------------
__global__ __launch_bounds__(256) void gemm2_fused(
    const unsigned short* __restrict__ y1,
    const unsigned short* __restrict__ W, const float* __restrict__ bias,
    const float* __restrict__ sum1, const float* __restrict__ sq1,
    const float* __restrict__ gamma1, const float* __restrict__ beta1,
    unsigned short* __restrict__ out, float* __restrict__ sum, float* __restrict__ sq,
    float invN)
{
    __shared__ unsigned short Abuf[2][8 * 512];
    __shared__ unsigned short Bbuf[2][8 * 512];
    __shared__ float scs[256], shs[256];
    const int tid = threadIdx.x;
    const int w = tid >> 6, lane = tid & 63;
    const int bid = blockIdx.x;
    const int xcd = bid & 7, q = bid >> 3;
    const int cb = q & 1, y = (q >> 1) * 8 + xcd;
    const int rowBase = y * 128, colBase = cb * 128;
    const int lr = lane & 15, lq = lane >> 4;
    const int wm = w >> 1, wn = w & 1;

    {   // per-column bn1 scale/shift (identical arithmetic to bnrelu)
        const float mean = sum1[tid] * invN;
        const float var  = sq1[tid] * invN - mean * mean;
        const float rstd = rsqrtf(var + 1e-5f);
        const float sc = gamma1[tid] * rstd;
        scs[tid] = sc;
        shs[tid] = beta1[tid] - mean * sc;
    }

    f32x4 acc[4][4];
    #pragma unroll
    for (int i = 0; i < 4; ++i)
        #pragma unroll
        for (int j = 0; j < 4; ++j) { f32x4 z = {0.f, 0.f, 0.f, 0.f}; acc[i][j] = z; }

    bf16x8 rawA[2];
    auto loadA = [&](int ks) {
        #pragma unroll
        for (int s = 0; s < 2; ++s) {
            const int sub = 2 * w + s;
            rawA[s] = *(const bf16x8*)&y1[(size_t)(rowBase + sub * 16 + lr) * 256 + ks * 32 + lq * 8];
        }
    };
    auto writeA = [&](int ks, int bi) {
        const int k0 = ks * 32 + lq * 8;
        #pragma unroll
        for (int s = 0; s < 2; ++s) {
            const int sub = 2 * w + s;
            bf16x8 o;
            #pragma unroll
            for (int j = 0; j < 8; ++j)
                o[j] = (short)f2bf(fmaxf(bfe2f(rawA[s][j]) * scs[k0 + j] + shs[k0 + j], 0.f));
            *(bf16x8*)&Abuf[bi][sub * 512 + lane * 8] = o;
        }
    };
    auto stageB = [&](int ks, int bi) {
        #pragma unroll
        for (int s = 0; s < 2; ++s) {
            const int sub = 2 * w + s;
            gl_lds16(W + (size_t)(colBase + sub * 16 + lr) * 256 + ks * 32 + lq * 8,
                     &Bbuf[bi][sub * 512]);
        }
    };
    auto compute = [&](int bi) {
        bf16x8 af[4], bfr[4];
        #pragma unroll
        for (int i = 0; i < 4; ++i) af[i] = *(const bf16x8*)&Abuf[bi][(wm * 4 + i) * 512 + lane * 8];
        #pragma unroll
        for (int j = 0; j < 4; ++j) bfr[j] = *(const bf16x8*)&Bbuf[bi][(wn * 4 + j) * 512 + lane * 8];
        #pragma unroll
        for (int i = 0; i < 4; ++i)
            #pragma unroll
            for (int j = 0; j < 4; ++j)
                acc[i][j] = __builtin_amdgcn_mfma_f32_16x16x32_bf16(af[i], bfr[j], acc[i][j], 0, 0, 0);
    };

    __syncthreads();                     // scs/shs visible
    loadA(0); stageB(0, 0); writeA(0, 0);
    __syncthreads();                     // Abuf[0] written, Bbuf[0] landed
    for (int ks = 0; ks < 8; ++ks) {
        const int cur = ks & 1;
        if (ks + 1 < 8) { loadA(ks + 1); stageB(ks + 1, cur ^ 1); }
        compute(cur);
        if (ks + 1 < 8) writeA(ks + 1, cur ^ 1);
        __syncthreads();
    }

    const int col0 = colBase + wn * 64;
    #pragma unroll
    for (int j = 0; j < 4; ++j) {
        const int col = col0 + j * 16 + lr;
        const float bv = bias[col];
        float cs = 0.f, cq = 0.f;
        #pragma unroll
        for (int i = 0; i < 4; ++i) {
            const int row0 = rowBase + wm * 64 + i * 16 + lq * 4;
            #pragma unroll
            for (int r = 0; r < 4; ++r) {
                const float v = acc[i][j][r] + bv;
                cs += v; cq += v * v;
                out[(size_t)(row0 + r) * 256 + col] = f2bf(v);
            }
        }
        cs += __shfl_xor(cs, 16); cs += __shfl_xor(cs, 32);
        cq += __shfl_xor(cq, 16); cq += __shfl_xor(cq, 32);
        if (lq == 0) { atomicAdd(&sum[col], cs); atomicAdd(&sq[col], cq); }
    }
}

// ---------------------------------------------------------------------------
// epilogue: out = dst + bn2(y2bf), finalize inlined. 8 elems/thread.
// ---------------------------------------------------------------------------
__global__ __launch_bounds__(256) void epilogue_kernel(
    const float* __restrict__ dst, const unsigned short* __restrict__ y2,
    const float* __restrict__ sum, const float* __restrict__ sq,
    const float* __restrict__ gamma, const float* __restrict__ beta,
    float* __restrict__ out, int n8, float invN)
{
    const int i = blockIdx.x * 256 + threadIdx.x;
    if (i >= n8) return;
    const int j0 = (i & 31) * 8;
    const bf16x8 yv = ((const bf16x8*)y2)[i];
    const float4 d0 = ((const float4*)dst)[2 * i];
    const float4 d1 = ((const float4*)dst)[2 * i + 1];
    float o[8];
    const float dv[8] = {d0.x, d0.y, d0.z, d0.w, d1.x, d1.y, d1.z, d1.w};
    #pragma unroll
    for (int j = 0; j < 8; ++j) {
        const float mean = sum[j0 + j] * invN;
        const float var  = sq[j0 + j] * invN - mean * mean;
        const float rstd = rsqrtf(var + 1e-5f);
        const float sc = gamma[j0 + j] * rstd;
        const float sh = beta[j0 + j] - mean * sc;
        o[j] = dv[j] + bfe2f(yv[j]) * sc + sh;
    }
    float4 o0, o1;
    o0.x = o[0]; o0.y = o[1]; o0.z = o[2]; o0.w = o[3];
    o1.x = o[4]; o1.y = o[5]; o1.z = o[6]; o1.w = o[7];
    ((float4*)out)[2 * i]     = o0;
    ((float4*)out)[2 * i + 1] = o1;
}

// ---------------------------------------------------------------------------
extern "C" void kernel_launch(void* const* d_in, const int* in_sizes, int n_in,
                              void* d_out, int out_size, void* d_ws, size_t ws_size,
                              hipStream_t stream)
{
    const float* src_h  = (const float*)d_in[0];
    const float* dst_h  = (const float*)d_in[1];
    const int*   slen   = (const int*)d_in[2];
    const int*   dlen   = (const int*)d_in[3];
    const float* W1     = (const float*)d_in[4];
    const float* b1     = (const float*)d_in[5];
    const float* gamma1 = (const float*)d_in[6];
    const float* beta1  = (const float*)d_in[7];
    const float* W2     = (const float*)d_in[8];
    const float* b2     = (const float*)d_in[9];
    const float* gamma2 = (const float*)d_in[10];
    const float* beta2  = (const float*)d_in[11];
    float* out = (float*)d_out;

    const int N = in_sizes[1] / H;     // 40960
    const int B = in_sizes[2];         // 512

    // ---- workspace layout (bytes) ----
    char* base = (char*)d_ws;
    int*   soff   = (int*)(base + 0);            // 2KB
    int*   doff   = (int*)(base + 2048);         // 2KB
    float* stats  = (float*)(base + 4096);       // 4KB: sum1, sq1, sum2, sq2
    unsigned short* W1p  = (unsigned short*)(base + 16384);            // 256KB
    unsigned short* W2bf = (unsigned short*)(base + 16384 + 262144);   // 128KB
    const size_t S = (size_t)N * H * sizeof(unsigned short);           // 21 MB
    char* big = base + (1 << 20);
    unsigned short* KT  = (unsigned short*)(big);
    unsigned short* VT2 = (unsigned short*)(big + S);
    unsigned short* QT  = (unsigned short*)(big + 2 * S);
    unsigned short* OT  = (unsigned short*)(big + 3 * S);
    unsigned short* y1bf = KT;    // reuse after attention
    unsigned short* y2bf = QT;    // reuse after gemm1 (gemm2 reads y1bf only)

    const float invN = 1.0f / (float)N;

    const int prepB = N >> 5;                       // 1280
    pre_kernel<<<prepB + 768 + 1, 256, 0, stream>>>(
        src_h, dst_h, W1, W2, slen, dlen,
        KT, VT2, QT, W1p, W2bf, soff, doff, stats, N, B);

    attn_mfma<<<B * 2, 256, 0, stream>>>(KT, QT, VT2, OT, soff, doff, slen, dlen, N);

    // 640 blocks = 320 row panels x 2 col blocks, XCD-paired
    gemm1_mfma<<<640, 256, 0, stream>>>(QT, OT, W1p, b1, y1bf, stats + 0, stats + 256, N);

    gemm2_fused<<<640, 256, 0, stream>>>(
        y1bf, W2bf, b2, stats + 0, stats + 256, gamma1, beta1,
        y2bf, stats + 512, stats + 768, invN);

    const int n8 = N * H / 8;
    epilogue_kernel<<<(n8 + 255) / 256, 256, 0, stream>>>(
        dst_h, y2bf, stats + 512, stats + 768, gamma2, beta2, out, n8, invN);
}

// Round 11
// 250.459 us; speedup vs baseline: 1.0335x; 1.0018x over previous
//
#include <hip/hip_runtime.h>
#include <cstddef>

#define H 256
#define NHEADS 8
#define HD 32

typedef __attribute__((ext_vector_type(8))) short bf16x8;
typedef __attribute__((ext_vector_type(4))) float f32x4;

__device__ __forceinline__ float bf2f(unsigned short s) {
    unsigned u = ((unsigned)s) << 16; return __builtin_bit_cast(float, u);
}
__device__ __forceinline__ float bfe2f(short s) {
    unsigned u = ((unsigned)(unsigned short)s) << 16; return __builtin_bit_cast(float, u);
}
__device__ __forceinline__ unsigned short f2bf(float x) {
    unsigned u = __builtin_bit_cast(unsigned, x);
    u += 0x7fffu + ((u >> 16) & 1u);           // round-to-nearest-even
    return (unsigned short)(u >> 16);
}
__device__ __forceinline__ void gl_lds16(const void* g, void* l) {
    __builtin_amdgcn_global_load_lds(
        (const __attribute__((address_space(1))) void*)g,
        (__attribute__((address_space(3))) void*)l, 16, 0, 0);
}

// ---------------------------------------------------------------------------
// PRE: merged {prepass | cvtW | scan+zero} in one launch. 64-row prepass
// blocks (R6/R9 config, 41.1us known-good; 32-row split regressed to 45).
// Row stride 42 shorts: VT2 gather nc-stride 336 shorts == 8 mod 32 dwords
// -> 4-way; plane stride PS=2696 == 4 mod 32 dwords -> 2-way (free).
// ---------------------------------------------------------------------------
#define PS 2696
__global__ __launch_bounds__(256) void pre_kernel(
    const float* __restrict__ src, const float* __restrict__ dst,
    const float* __restrict__ W1, const float* __restrict__ W2,
    const int* __restrict__ slen, const int* __restrict__ dlen,
    unsigned short* __restrict__ KT, unsigned short* __restrict__ VT2,
    unsigned short* __restrict__ QT,
    unsigned short* __restrict__ W1p, unsigned short* __restrict__ W2bf,
    int* __restrict__ soff, int* __restrict__ doff,
    float* __restrict__ stats, int N, int B)
{
    __shared__ unsigned short pl[8 * PS];
    const int t = threadIdx.x;
    const int bid = blockIdx.x;
    const int prepB = N >> 5;                    // (N/64)*2

    if (bid < prepB) {
        // ---- prepass ----
        const int rb = (bid >> 1) * 64;
        const int isrc = (bid & 1) == 0;
        const float* __restrict__ in = isrc ? src : dst;
        unsigned short* __restrict__ T = isrc ? KT : QT;
        #pragma unroll
        for (int i = 0; i < 16; ++i) {
            const int idx = t + i * 256;         // 4096 float4s
            const int row = idx >> 6, f4 = idx & 63;
            const float4 v = ((const float4*)in)[(size_t)(rb + row) * 64 + f4];
            const int f0 = f4 * 4, h0 = f0 & 7, d = f0 >> 3;
            pl[(h0 + 0) * PS + row * 42 + d] = f2bf(v.x);
            pl[(h0 + 1) * PS + row * 42 + d] = f2bf(v.y);
            pl[(h0 + 2) * PS + row * 42 + d] = f2bf(v.z);
            pl[(h0 + 3) * PS + row * 42 + d] = f2bf(v.w);
        }
        __syncthreads();
        #pragma unroll
        for (int i = 0; i < 8; ++i) {
            const int idx = t + i * 256;         // 2048 16B chunks
            const int h = idx >> 8, rem = idx & 255, row = rem >> 2, c = rem & 3;
            const bf16x8 val = *(const bf16x8*)&pl[h * PS + row * 42 + c * 8];
            *(bf16x8*)&T[(size_t)(h * N + rb + row) * 32 + c * 8] = val;
        }
        if (isrc) {
            #pragma unroll
            for (int i = 0; i < 8; ++i) {
                const int idx = t + i * 256;     // 8 planes x 32 d x 8 n-chunks
                const int h = idx >> 8, rem = idx & 255, d = rem >> 3, nc = rem & 7;
                bf16x8 v8;
                #pragma unroll
                for (int j = 0; j < 8; ++j)
                    v8[j] = (short)pl[h * PS + (nc * 8 + j) * 42 + d];
                *(bf16x8*)&VT2[(size_t)(h * 32 + d) * N + rb + nc * 8] = v8;
            }
        }
    } else if (bid < prepB + 768) {
        // ---- weights cvt: W1 K-permuted (kp = half*256 + h*32 + d), W2 plain
        const int idx = (bid - prepB) * 256 + t;
        if (idx < 131072) {
            const int kp = idx & 511, c = idx >> 9;
            const int half = kp >> 8, r = kp & 255, hh = r >> 5, d = r & 31;
            W1p[(size_t)c * 512 + kp] = f2bf(W1[(size_t)c * 512 + half * 256 + d * 8 + hh]);
        } else {
            const int i2 = idx - 131072;
            W2bf[i2] = f2bf(W2[i2]);
        }
    } else {
        // ---- stats zero + lens exclusive scan (one wave, shfl-scan) ----
        stats[t] = 0.f; stats[t + 256] = 0.f; stats[t + 512] = 0.f; stats[t + 768] = 0.f;
        if (t < 64) {
            int sv[8], dv[8];
            int sl = 0, dl = 0;
            #pragma unroll
            for (int j = 0; j < 8; ++j) {
                const int g = t * 8 + j;
                sv[j] = sl; dv[j] = dl;
                sl += (g < B) ? slen[g] : 0;
                dl += (g < B) ? dlen[g] : 0;
            }
            int sx = sl, dx = dl;
            #pragma unroll
            for (int o = 1; o < 64; o <<= 1) {
                const int sy = __shfl_up(sx, o);
                const int dy = __shfl_up(dx, o);
                if (t >= o) { sx += sy; dx += dy; }
            }
            const int sbase = sx - sl, dbase = dx - dl;
            #pragma unroll
            for (int j = 0; j < 8; ++j) {
                const int g = t * 8 + j;
                if (g < B) { soff[g] = sbase + sv[j]; doff[g] = dbase + dv[j]; }
            }
        }
    }
}

// ---------------------------------------------------------------------------
// K2: MFMA attention (one wave per (graph, head)); Q double-buffered.
// T5 setprio around MFMA clusters (m191 regime: independent waves, no
// cross-wave sync). LPT remap: heavy graphs dispatch first.
// ---------------------------------------------------------------------------
template<int LS>
__device__ __forceinline__ void attn_body(
    const unsigned short* __restrict__ KT, const unsigned short* __restrict__ QT,
    const unsigned short* __restrict__ VT2, unsigned short* __restrict__ OT,
    unsigned short* __restrict__ Ps, int N, int so, int df, int Ld, int h, int lane)
{
    constexpr int MT = LS / 16, CH = LS / 32;
    const int lr = lane & 15, lq = lane >> 4;
    const float iscale = 0.17677669529663687f;  // 1/sqrt(32)

    bf16x8 kf[MT];
    #pragma unroll
    for (int mt = 0; mt < MT; ++mt)
        kf[mt] = *(const bf16x8*)&KT[(size_t)(h * N + so + mt * 16 + lr) * 32 + lq * 8];
    bf16x8 vf[CH][2];
    #pragma unroll
    for (int c = 0; c < CH; ++c)
        #pragma unroll
        for (int dt = 0; dt < 2; ++dt)
            vf[c][dt] = *(const bf16x8*)&VT2[(size_t)(h * 32 + dt * 16 + lr) * N + so + c * 32 + lq * 8];

    const int NT = Ld >> 4;
    bf16x8 qf = *(const bf16x8*)&QT[(size_t)(h * N + df + lr) * 32 + lq * 8];
    for (int nt = 0; nt < NT; ++nt) {
        bf16x8 qn = qf;
        if (nt + 1 < NT)
            qn = *(const bf16x8*)&QT[(size_t)(h * N + df + (nt + 1) * 16 + lr) * 32 + lq * 8];
        f32x4 s[MT];
        __builtin_amdgcn_s_setprio(1);
        #pragma unroll
        for (int mt = 0; mt < MT; ++mt) {
            f32x4 z = {0.f, 0.f, 0.f, 0.f};
            s[mt] = __builtin_amdgcn_mfma_f32_16x16x32_bf16(kf[mt], qf, z, 0, 0, 0);
        }
        __builtin_amdgcn_s_setprio(0);
        float mx = -INFINITY;
        #pragma unroll
        for (int mt = 0; mt < MT; ++mt)
            mx = fmaxf(mx, fmaxf(fmaxf(s[mt][0], s[mt][1]), fmaxf(s[mt][2], s[mt][3])));
        mx = fmaxf(mx, __shfl_xor(mx, 16));
        mx = fmaxf(mx, __shfl_xor(mx, 32));
        const float mxi = mx * iscale;
        float sum = 0.f;
        #pragma unroll
        for (int mt = 0; mt < MT; ++mt) {
            #pragma unroll
            for (int r = 0; r < 4; ++r) {
                const float e = __expf(s[mt][r] * iscale - mxi);
                s[mt][r] = e; sum += e;
            }
        }
        sum += __shfl_xor(sum, 16);
        sum += __shfl_xor(sum, 32);
        const float rinv = 1.f / sum;
        #pragma unroll
        for (int mt = 0; mt < MT; ++mt) {
            uint2 p;
            p.x = ((unsigned)f2bf(s[mt][0])) | (((unsigned)f2bf(s[mt][1])) << 16);
            p.y = ((unsigned)f2bf(s[mt][2])) | (((unsigned)f2bf(s[mt][3])) << 16);
            *(uint2*)&Ps[lr * 136 + mt * 16 + lq * 4] = p;
        }
        __asm__ volatile("" ::: "memory");
        __builtin_amdgcn_wave_barrier();
        f32x4 o0 = {0.f, 0.f, 0.f, 0.f}, o1 = {0.f, 0.f, 0.f, 0.f};
        __builtin_amdgcn_s_setprio(1);
        #pragma unroll
        for (int c = 0; c < CH; ++c) {
            const bf16x8 pa = *(const bf16x8*)&Ps[lr * 136 + c * 32 + lq * 8];
            o0 = __builtin_amdgcn_mfma_f32_16x16x32_bf16(pa, vf[c][0], o0, 0, 0, 0);
            o1 = __builtin_amdgcn_mfma_f32_16x16x32_bf16(pa, vf[c][1], o1, 0, 0, 0);
        }
        __builtin_amdgcn_s_setprio(0);
        __asm__ volatile("" ::: "memory");
        __builtin_amdgcn_wave_barrier();
        #pragma unroll
        for (int r = 0; r < 4; ++r) {
            const float rv = __shfl(rinv, lq * 4 + r);
            const int row = df + nt * 16 + lq * 4 + r;
            OT[(size_t)(h * N + row) * 32 + lr]      = f2bf(o0[r] * rv);
            OT[(size_t)(h * N + row) * 32 + 16 + lr] = f2bf(o1[r] * rv);
        }
        qf = qn;
    }
}

// LPT remap: heavy (l=128) graphs dispatch first, light (l=32) pack the tail.
__global__ __launch_bounds__(256) void attn_mfma(
    const unsigned short* __restrict__ KT, const unsigned short* __restrict__ QT,
    const unsigned short* __restrict__ VT2, unsigned short* __restrict__ OT,
    const int* __restrict__ soff, const int* __restrict__ doff,
    const int* __restrict__ slen, const int* __restrict__ dlen, int N)
{
    __shared__ unsigned short Ps[4][16 * 136];
    const int i = blockIdx.x >> 1, half = blockIdx.x & 1;
    const int grp = i >> 7, j = i & 127;
    const int b = 4 * j + (3 - grp);             // bijective over [0,512)
    const int w = threadIdx.x >> 6, lane = threadIdx.x & 63;
    const int h = half * 4 + w;
    const int Ls = slen[b], Ld = dlen[b], so = soff[b], df = doff[b];
    switch (Ls) {
        case 32:  attn_body<32> (KT, QT, VT2, OT, Ps[w], N, so, df, Ld, h, lane); break;
        case 64:  attn_body<64> (KT, QT, VT2, OT, Ps[w], N, so, df, Ld, h, lane); break;
        case 96:  attn_body<96> (KT, QT, VT2, OT, Ps[w], N, so, df, Ld, h, lane); break;
        default:  attn_body<128>(KT, QT, VT2, OT, Ps[w], N, so, df, Ld, h, lane); break;
    }
}

// ---------------------------------------------------------------------------
// K3: GEMM1 (128x128, BK=32, depth-1 dbuf, XCD swizzle; R9 exact).
// ---------------------------------------------------------------------------
__global__ __launch_bounds__(256) void gemm1_mfma(
    const unsigned short* __restrict__ QT, const unsigned short* __restrict__ OT,
    const unsigned short* __restrict__ W, const float* __restrict__ bias,
    unsigned short* __restrict__ out, float* __restrict__ sum, float* __restrict__ sq,
    int N)
{
    __shared__ unsigned short Abuf[2][8 * 512];
    __shared__ unsigned short Bbuf[2][8 * 512];
    const int tid = threadIdx.x;
    const int w = tid >> 6, lane = tid & 63;
    // XCD swizzle decode: bid = 8*(2*(y/8)+cb) + (y%8)
    const int bid = blockIdx.x;
    const int xcd = bid & 7, q = bid >> 3;
    const int cb = q & 1, y = (q >> 1) * 8 + xcd;
    const int rowBase = y * 128, colBase = cb * 128;
    const int lr = lane & 15, lq = lane >> 4;
    const int wm = w >> 1, wn = w & 1;

    f32x4 acc[4][4];
    #pragma unroll
    for (int i = 0; i < 4; ++i)
        #pragma unroll
        for (int j = 0; j < 4; ++j) { f32x4 z = {0.f, 0.f, 0.f, 0.f}; acc[i][j] = z; }

    // K-step ks in [0,16): phase = ks>>3 (QT then OT), head hh = ks&7.
    auto stage = [&](int ks, int bi) {
        const unsigned short* __restrict__ Ap = (ks < 8) ? QT : OT;
        const int hh = ks & 7;
        #pragma unroll
        for (int s = 0; s < 2; ++s) {
            const int sub = 2 * w + s;
            gl_lds16(Ap + (size_t)(hh * N + rowBase + sub * 16 + lr) * 32 + lq * 8,
                     &Abuf[bi][sub * 512]);
            gl_lds16(W + (size_t)(colBase + sub * 16 + lr) * 512 + ks * 32 + lq * 8,
                     &Bbuf[bi][sub * 512]);
        }
    };
    auto compute = [&](int bi) {
        bf16x8 af[4], bfr[4];
        #pragma unroll
        for (int i = 0; i < 4; ++i) af[i] = *(const bf16x8*)&Abuf[bi][(wm * 4 + i) * 512 + lane * 8];
        #pragma unroll
        for (int j = 0; j < 4; ++j) bfr[j] = *(const bf16x8*)&Bbuf[bi][(wn * 4 + j) * 512 + lane * 8];
        #pragma unroll
        for (int i = 0; i < 4; ++i)
            #pragma unroll
            for (int j = 0; j < 4; ++j)
                acc[i][j] = __builtin_amdgcn_mfma_f32_16x16x32_bf16(af[i], bfr[j], acc[i][j], 0, 0, 0);
    };

    stage(0, 0);
    __syncthreads();
    for (int ks = 0; ks < 16; ks += 2) {
        stage(ks + 1, 1);
        compute(0);
        __syncthreads();
        if (ks + 2 < 16) stage(ks + 2, 0);
        compute(1);
        __syncthreads();
    }

    const int col0 = colBase + wn * 64;
    #pragma unroll
    for (int j = 0; j < 4; ++j) {
        const int col = col0 + j * 16 + lr;
        const float bv = bias[col];
        float cs = 0.f, cq = 0.f;
        #pragma unroll
        for (int i = 0; i < 4; ++i) {
            const int row0 = rowBase + wm * 64 + i * 16 + lq * 4;
            #pragma unroll
            for (int r = 0; r < 4; ++r) {
                const float v = acc[i][j][r] + bv;
                cs += v; cq += v * v;
                out[(size_t)(row0 + r) * 256 + col] = f2bf(v);
            }
        }
        cs += __shfl_xor(cs, 16); cs += __shfl_xor(cs, 32);
        cq += __shfl_xor(cq, 16); cq += __shfl_xor(cq, 32);
        if (lq == 0) { atomicAdd(&sum[col], cs); atomicAdd(&sq[col], cq); }
    }
}

// ---------------------------------------------------------------------------
// K5: GEMM2 with FUSED bn1+relu on the A path + XCD swizzle (R9 exact).
// ---------------------------------------------------------------------------
__global__ __launch_bounds__(256) void gemm2_fused(
    const unsigned short* __restrict__ y1,
    const unsigned short* __restrict__ W, const float* __restrict__ bias,
    const float* __restrict__ sum1, const float* __restrict__ sq1,
    const float* __restrict__ gamma1, const float* __restrict__ beta1,
    unsigned short* __restrict__ out, float* __restrict__ sum, float* __restrict__ sq,
    float invN)
{
    __shared__ unsigned short Abuf[2][8 * 512];
    __shared__ unsigned short Bbuf[2][8 * 512];
    __shared__ float scs[256], shs[256];
    const int tid = threadIdx.x;
    const int w = tid >> 6, lane = tid & 63;
    const int bid = blockIdx.x;
    const int xcd = bid & 7, q = bid >> 3;
    const int cb = q & 1, y = (q >> 1) * 8 + xcd;
    const int rowBase = y * 128, colBase = cb * 128;
    const int lr = lane & 15, lq = lane >> 4;
    const int wm = w >> 1, wn = w & 1;

    {   // per-column bn1 scale/shift (identical arithmetic to bnrelu)
        const float mean = sum1[tid] * invN;
        const float var  = sq1[tid] * invN - mean * mean;
        const float rstd = rsqrtf(var + 1e-5f);
        const float sc = gamma1[tid] * rstd;
        scs[tid] = sc;
        shs[tid] = beta1[tid] - mean * sc;
    }

    f32x4 acc[4][4];
    #pragma unroll
    for (int i = 0; i < 4; ++i)
        #pragma unroll
        for (int j = 0; j < 4; ++j) { f32x4 z = {0.f, 0.f, 0.f, 0.f}; acc[i][j] = z; }

    bf16x8 rawA[2];
    auto loadA = [&](int ks) {
        #pragma unroll
        for (int s = 0; s < 2; ++s) {
            const int sub = 2 * w + s;
            rawA[s] = *(const bf16x8*)&y1[(size_t)(rowBase + sub * 16 + lr) * 256 + ks * 32 + lq * 8];
        }
    };
    auto writeA = [&](int ks, int bi) {
        const int k0 = ks * 32 + lq * 8;
        #pragma unroll
        for (int s = 0; s < 2; ++s) {
            const int sub = 2 * w + s;
            bf16x8 o;
            #pragma unroll
            for (int j = 0; j < 8; ++j)
                o[j] = (short)f2bf(fmaxf(bfe2f(rawA[s][j]) * scs[k0 + j] + shs[k0 + j], 0.f));
            *(bf16x8*)&Abuf[bi][sub * 512 + lane * 8] = o;
        }
    };
    auto stageB = [&](int ks, int bi) {
        #pragma unroll
        for (int s = 0; s < 2; ++s) {
            const int sub = 2 * w + s;
            gl_lds16(W + (size_t)(colBase + sub * 16 + lr) * 256 + ks * 32 + lq * 8,
                     &Bbuf[bi][sub * 512]);
        }
    };
    auto compute = [&](int bi) {
        bf16x8 af[4], bfr[4];
        #pragma unroll
        for (int i = 0; i < 4; ++i) af[i] = *(const bf16x8*)&Abuf[bi][(wm * 4 + i) * 512 + lane * 8];
        #pragma unroll
        for (int j = 0; j < 4; ++j) bfr[j] = *(const bf16x8*)&Bbuf[bi][(wn * 4 + j) * 512 + lane * 8];
        #pragma unroll
        for (int i = 0; i < 4; ++i)
            #pragma unroll
            for (int j = 0; j < 4; ++j)
                acc[i][j] = __builtin_amdgcn_mfma_f32_16x16x32_bf16(af[i], bfr[j], acc[i][j], 0, 0, 0);
    };

    __syncthreads();                     // scs/shs visible
    loadA(0); stageB(0, 0); writeA(0, 0);
    __syncthreads();                     // Abuf[0] written, Bbuf[0] landed
    for (int ks = 0; ks < 8; ++ks) {
        const int cur = ks & 1;
        if (ks + 1 < 8) { loadA(ks + 1); stageB(ks + 1, cur ^ 1); }
        compute(cur);
        if (ks + 1 < 8) writeA(ks + 1, cur ^ 1);
        __syncthreads();
    }

    const int col0 = colBase + wn * 64;
    #pragma unroll
    for (int j = 0; j < 4; ++j) {
        const int col = col0 + j * 16 + lr;
        const float bv = bias[col];
        float cs = 0.f, cq = 0.f;
        #pragma unroll
        for (int i = 0; i < 4; ++i) {
            const int row0 = rowBase + wm * 64 + i * 16 + lq * 4;
            #pragma unroll
            for (int r = 0; r < 4; ++r) {
                const float v = acc[i][j][r] + bv;
                cs += v; cq += v * v;
                out[(size_t)(row0 + r) * 256 + col] = f2bf(v);
            }
        }
        cs += __shfl_xor(cs, 16); cs += __shfl_xor(cs, 32);
        cq += __shfl_xor(cq, 16); cq += __shfl_xor(cq, 32);
        if (lq == 0) { atomicAdd(&sum[col], cs); atomicAdd(&sq[col], cq); }
    }
}

// ---------------------------------------------------------------------------
// epilogue: out = dst + bn2(y2bf), finalize inlined. 8 elems/thread.
// ---------------------------------------------------------------------------
__global__ __launch_bounds__(256) void epilogue_kernel(
    const float* __restrict__ dst, const unsigned short* __restrict__ y2,
    const float* __restrict__ sum, const float* __restrict__ sq,
    const float* __restrict__ gamma, const float* __restrict__ beta,
    float* __restrict__ out, int n8, float invN)
{
    const int i = blockIdx.x * 256 + threadIdx.x;
    if (i >= n8) return;
    const int j0 = (i & 31) * 8;
    const bf16x8 yv = ((const bf16x8*)y2)[i];
    const float4 d0 = ((const float4*)dst)[2 * i];
    const float4 d1 = ((const float4*)dst)[2 * i + 1];
    float o[8];
    const float dv[8] = {d0.x, d0.y, d0.z, d0.w, d1.x, d1.y, d1.z, d1.w};
    #pragma unroll
    for (int j = 0; j < 8; ++j) {
        const float mean = sum[j0 + j] * invN;
        const float var  = sq[j0 + j] * invN - mean * mean;
        const float rstd = rsqrtf(var + 1e-5f);
        const float sc = gamma[j0 + j] * rstd;
        const float sh = beta[j0 + j] - mean * sc;
        o[j] = dv[j] + bfe2f(yv[j]) * sc + sh;
    }
    float4 o0, o1;
    o0.x = o[0]; o0.y = o[1]; o0.z = o[2]; o0.w = o[3];
    o1.x = o[4]; o1.y = o[5]; o1.z = o[6]; o1.w = o[7];
    ((float4*)out)[2 * i]     = o0;
    ((float4*)out)[2 * i + 1] = o1;
}

// ---------------------------------------------------------------------------
extern "C" void kernel_launch(void* const* d_in, const int* in_sizes, int n_in,
                              void* d_out, int out_size, void* d_ws, size_t ws_size,
                              hipStream_t stream)
{
    const float* src_h  = (const float*)d_in[0];
    const float* dst_h  = (const float*)d_in[1];
    const int*   slen   = (const int*)d_in[2];
    const int*   dlen   = (const int*)d_in[3];
    const float* W1     = (const float*)d_in[4];
    const float* b1     = (const float*)d_in[5];
    const float* gamma1 = (const float*)d_in[6];
    const float* beta1  = (const float*)d_in[7];
    const float* W2     = (const float*)d_in[8];
    const float* b2     = (const float*)d_in[9];
    const float* gamma2 = (const float*)d_in[10];
    const float* beta2  = (const float*)d_in[11];
    float* out = (float*)d_out;

    const int N = in_sizes[1] / H;     // 40960
    const int B = in_sizes[2];         // 512

    // ---- workspace layout (bytes) ----
    char* base = (char*)d_ws;
    int*   soff   = (int*)(base + 0);            // 2KB
    int*   doff   = (int*)(base + 2048);         // 2KB
    float* stats  = (float*)(base + 4096);       // 4KB: sum1, sq1, sum2, sq2
    unsigned short* W1p  = (unsigned short*)(base + 16384);            // 256KB
    unsigned short* W2bf = (unsigned short*)(base + 16384 + 262144);   // 128KB
    const size_t S = (size_t)N * H * sizeof(unsigned short);           // 21 MB
    char* big = base + (1 << 20);
    unsigned short* KT  = (unsigned short*)(big);
    unsigned short* VT2 = (unsigned short*)(big + S);
    unsigned short* QT  = (unsigned short*)(big + 2 * S);
    unsigned short* OT  = (unsigned short*)(big + 3 * S);
    unsigned short* y1bf = KT;    // reuse after attention
    unsigned short* y2bf = QT;    // reuse after gemm1 (gemm2 reads y1bf only)

    const float invN = 1.0f / (float)N;

    const int prepB = N >> 5;                       // 1280
    pre_kernel<<<prepB + 768 + 1, 256, 0, stream>>>(
        src_h, dst_h, W1, W2, slen, dlen,
        KT, VT2, QT, W1p, W2bf, soff, doff, stats, N, B);

    attn_mfma<<<B * 2, 256, 0, stream>>>(KT, QT, VT2, OT, soff, doff, slen, dlen, N);

    // 640 blocks = 320 row panels x 2 col blocks, XCD-paired
    gemm1_mfma<<<640, 256, 0, stream>>>(QT, OT, W1p, b1, y1bf, stats + 0, stats + 256, N);

    gemm2_fused<<<640, 256, 0, stream>>>(
        y1bf, W2bf, b2, stats + 0, stats + 256, gamma1, beta1,
        y2bf, stats + 512, stats + 768, invN);

    const int n8 = N * H / 8;
    epilogue_kernel<<<(n8 + 255) / 256, 256, 0, stream>>>(
        dst_h, y2bf, stats + 512, stats + 768, gamma2, beta2, out, n8, invN);
}

// Round 12
// 243.502 us; speedup vs baseline: 1.0630x; 1.0286x over previous
//
#include <hip/hip_runtime.h>
#include <cstddef>

#define H 256
#define NHEADS 8
#define HD 32

typedef __attribute__((ext_vector_type(8))) short bf16x8;
typedef __attribute__((ext_vector_type(4))) float f32x4;

__device__ __forceinline__ float bf2f(unsigned short s) {
    unsigned u = ((unsigned)s) << 16; return __builtin_bit_cast(float, u);
}
__device__ __forceinline__ float bfe2f(short s) {
    unsigned u = ((unsigned)(unsigned short)s) << 16; return __builtin_bit_cast(float, u);
}
__device__ __forceinline__ unsigned short f2bf(float x) {
    unsigned u = __builtin_bit_cast(unsigned, x);
    u += 0x7fffu + ((u >> 16) & 1u);           // round-to-nearest-even
    return (unsigned short)(u >> 16);
}
__device__ __forceinline__ void gl_lds16(const void* g, void* l) {
    __builtin_amdgcn_global_load_lds(
        (const __attribute__((address_space(1))) void*)g,
        (__attribute__((address_space(3))) void*)l, 16, 0, 0);
}

// ---------------------------------------------------------------------------
// PRE: merged {prepass | cvtW | scan+zero}. VT2 ELIMINATED: attention now
// transposes K in-wave (it already holds the full K tile in registers), so
// pre drops the 21MB VT2 store + 10.5M gather LDS reads. Writes 62->41 MB.
// ---------------------------------------------------------------------------
#define PS 2696
__global__ __launch_bounds__(256) void pre_kernel(
    const float* __restrict__ src, const float* __restrict__ dst,
    const float* __restrict__ W1, const float* __restrict__ W2,
    const int* __restrict__ slen, const int* __restrict__ dlen,
    unsigned short* __restrict__ KT, unsigned short* __restrict__ QT,
    unsigned short* __restrict__ W1p, unsigned short* __restrict__ W2bf,
    int* __restrict__ soff, int* __restrict__ doff,
    float* __restrict__ stats, int N, int B)
{
    __shared__ unsigned short pl[8 * PS];
    const int t = threadIdx.x;
    const int bid = blockIdx.x;
    const int prepB = N >> 5;                    // (N/64)*2

    if (bid < prepB) {
        // ---- prepass: [64 rows][256 f] f32 -> per-head [h][row][32] bf16 ----
        const int rb = (bid >> 1) * 64;
        const int isrc = (bid & 1) == 0;
        const float* __restrict__ in = isrc ? src : dst;
        unsigned short* __restrict__ T = isrc ? KT : QT;
        #pragma unroll
        for (int i = 0; i < 16; ++i) {
            const int idx = t + i * 256;         // 4096 float4s
            const int row = idx >> 6, f4 = idx & 63;
            const float4 v = ((const float4*)in)[(size_t)(rb + row) * 64 + f4];
            const int f0 = f4 * 4, h0 = f0 & 7, d = f0 >> 3;
            pl[(h0 + 0) * PS + row * 42 + d] = f2bf(v.x);
            pl[(h0 + 1) * PS + row * 42 + d] = f2bf(v.y);
            pl[(h0 + 2) * PS + row * 42 + d] = f2bf(v.z);
            pl[(h0 + 3) * PS + row * 42 + d] = f2bf(v.w);
        }
        __syncthreads();
        #pragma unroll
        for (int i = 0; i < 8; ++i) {
            const int idx = t + i * 256;         // 2048 16B chunks
            const int h = idx >> 8, rem = idx & 255, row = rem >> 2, c = rem & 3;
            const bf16x8 val = *(const bf16x8*)&pl[h * PS + row * 42 + c * 8];
            *(bf16x8*)&T[(size_t)(h * N + rb + row) * 32 + c * 8] = val;
        }
    } else if (bid < prepB + 768) {
        // ---- weights cvt: W1 K-permuted (kp = half*256 + h*32 + d), W2 plain
        const int idx = (bid - prepB) * 256 + t;
        if (idx < 131072) {
            const int kp = idx & 511, c = idx >> 9;
            const int half = kp >> 8, r = kp & 255, hh = r >> 5, d = r & 31;
            W1p[(size_t)c * 512 + kp] = f2bf(W1[(size_t)c * 512 + half * 256 + d * 8 + hh]);
        } else {
            const int i2 = idx - 131072;
            W2bf[i2] = f2bf(W2[i2]);
        }
    } else {
        // ---- stats zero + lens exclusive scan (one wave, shfl-scan) ----
        stats[t] = 0.f; stats[t + 256] = 0.f; stats[t + 512] = 0.f; stats[t + 768] = 0.f;
        if (t < 64) {
            int sv[8], dv[8];
            int sl = 0, dl = 0;
            #pragma unroll
            for (int j = 0; j < 8; ++j) {
                const int g = t * 8 + j;
                sv[j] = sl; dv[j] = dl;
                sl += (g < B) ? slen[g] : 0;
                dl += (g < B) ? dlen[g] : 0;
            }
            int sx = sl, dx = dl;
            #pragma unroll
            for (int o = 1; o < 64; o <<= 1) {
                const int sy = __shfl_up(sx, o);
                const int dy = __shfl_up(dx, o);
                if (t >= o) { sx += sy; dx += dy; }
            }
            const int sbase = sx - sl, dbase = dx - dl;
            #pragma unroll
            for (int j = 0; j < 8; ++j) {
                const int g = t * 8 + j;
                if (g < B) { soff[g] = sbase + sv[j]; doff[g] = dbase + dv[j]; }
            }
        }
    }
}

// ---------------------------------------------------------------------------
// K2: MFMA attention. V-fragments now built by in-wave LDS transpose of the
// K tile (the wave already holds all Ls x 32 of K in kf[]): per 32x32 chunk,
// scatter kf into a [32][33]-padded tile in the wave-private Ps region
// (stride-33 rows: <=2-way bank aliasing on writes = free, conflict-free
// b128 reads), wave_barrier, read vf fragments. vf values are bitwise
// identical to the old VT2 path -> same numerics. Saves the 21MB VT2 HBM
// read here + 21MB write in pre.
// ---------------------------------------------------------------------------
template<int LS>
__device__ __forceinline__ void attn_body(
    const unsigned short* __restrict__ KT, const unsigned short* __restrict__ QT,
    unsigned short* __restrict__ OT,
    unsigned short* __restrict__ Ps, int N, int so, int df, int Ld, int h, int lane)
{
    constexpr int MT = LS / 16, CH = LS / 32;
    const int lr = lane & 15, lq = lane >> 4;
    const float iscale = 0.17677669529663687f;  // 1/sqrt(32)

    bf16x8 kf[MT];
    #pragma unroll
    for (int mt = 0; mt < MT; ++mt)
        kf[mt] = *(const bf16x8*)&KT[(size_t)(h * N + so + mt * 16 + lr) * 32 + lq * 8];

    // ---- build vf[c][dt] = V[n][d] fragments by transposing kf via LDS ----
    bf16x8 vf[CH][2];
    #pragma unroll
    for (int c = 0; c < CH; ++c) {
        #pragma unroll
        for (int hf = 0; hf < 2; ++hf) {
            const bf16x8 kv = kf[2 * c + hf];
            const int nn = hf * 16 + lr;         // n within chunk
            #pragma unroll
            for (int k = 0; k < 8; ++k)
                Ps[(lq * 8 + k) * 33 + nn] = (unsigned short)kv[k];   // T[d][n]
        }
        __asm__ volatile("" ::: "memory");
        __builtin_amdgcn_wave_barrier();
        #pragma unroll
        for (int dt = 0; dt < 2; ++dt)
            vf[c][dt] = *(const bf16x8*)&Ps[(dt * 16 + lr) * 33 + lq * 8];
        __asm__ volatile("" ::: "memory");
        __builtin_amdgcn_wave_barrier();
    }

    const int NT = Ld >> 4;
    bf16x8 qf = *(const bf16x8*)&QT[(size_t)(h * N + df + lr) * 32 + lq * 8];
    for (int nt = 0; nt < NT; ++nt) {
        bf16x8 qn = qf;
        if (nt + 1 < NT)
            qn = *(const bf16x8*)&QT[(size_t)(h * N + df + (nt + 1) * 16 + lr) * 32 + lq * 8];
        f32x4 s[MT];
        __builtin_amdgcn_s_setprio(1);
        #pragma unroll
        for (int mt = 0; mt < MT; ++mt) {
            f32x4 z = {0.f, 0.f, 0.f, 0.f};
            s[mt] = __builtin_amdgcn_mfma_f32_16x16x32_bf16(kf[mt], qf, z, 0, 0, 0);
        }
        __builtin_amdgcn_s_setprio(0);
        float mx = -INFINITY;
        #pragma unroll
        for (int mt = 0; mt < MT; ++mt)
            mx = fmaxf(mx, fmaxf(fmaxf(s[mt][0], s[mt][1]), fmaxf(s[mt][2], s[mt][3])));
        mx = fmaxf(mx, __shfl_xor(mx, 16));
        mx = fmaxf(mx, __shfl_xor(mx, 32));
        const float mxi = mx * iscale;
        float sum = 0.f;
        #pragma unroll
        for (int mt = 0; mt < MT; ++mt) {
            #pragma unroll
            for (int r = 0; r < 4; ++r) {
                const float e = __expf(s[mt][r] * iscale - mxi);
                s[mt][r] = e; sum += e;
            }
        }
        sum += __shfl_xor(sum, 16);
        sum += __shfl_xor(sum, 32);
        const float rinv = 1.f / sum;
        #pragma unroll
        for (int mt = 0; mt < MT; ++mt) {
            uint2 p;
            p.x = ((unsigned)f2bf(s[mt][0])) | (((unsigned)f2bf(s[mt][1])) << 16);
            p.y = ((unsigned)f2bf(s[mt][2])) | (((unsigned)f2bf(s[mt][3])) << 16);
            *(uint2*)&Ps[lr * 136 + mt * 16 + lq * 4] = p;
        }
        __asm__ volatile("" ::: "memory");
        __builtin_amdgcn_wave_barrier();
        f32x4 o0 = {0.f, 0.f, 0.f, 0.f}, o1 = {0.f, 0.f, 0.f, 0.f};
        __builtin_amdgcn_s_setprio(1);
        #pragma unroll
        for (int c = 0; c < CH; ++c) {
            const bf16x8 pa = *(const bf16x8*)&Ps[lr * 136 + c * 32 + lq * 8];
            o0 = __builtin_amdgcn_mfma_f32_16x16x32_bf16(pa, vf[c][0], o0, 0, 0, 0);
            o1 = __builtin_amdgcn_mfma_f32_16x16x32_bf16(pa, vf[c][1], o1, 0, 0, 0);
        }
        __builtin_amdgcn_s_setprio(0);
        __asm__ volatile("" ::: "memory");
        __builtin_amdgcn_wave_barrier();
        #pragma unroll
        for (int r = 0; r < 4; ++r) {
            const float rv = __shfl(rinv, lq * 4 + r);
            const int row = df + nt * 16 + lq * 4 + r;
            OT[(size_t)(h * N + row) * 32 + lr]      = f2bf(o0[r] * rv);
            OT[(size_t)(h * N + row) * 32 + 16 + lr] = f2bf(o1[r] * rv);
        }
        qf = qn;
    }
}

// LPT remap: heavy (l=128) graphs dispatch first, light (l=32) pack the tail.
__global__ __launch_bounds__(256) void attn_mfma(
    const unsigned short* __restrict__ KT, const unsigned short* __restrict__ QT,
    unsigned short* __restrict__ OT,
    const int* __restrict__ soff, const int* __restrict__ doff,
    const int* __restrict__ slen, const int* __restrict__ dlen, int N)
{
    __shared__ unsigned short Ps[4][16 * 136];
    const int i = blockIdx.x >> 1, half = blockIdx.x & 1;
    const int grp = i >> 7, j = i & 127;
    const int b = 4 * j + (3 - grp);             // bijective over [0,512)
    const int w = threadIdx.x >> 6, lane = threadIdx.x & 63;
    const int h = half * 4 + w;
    const int Ls = slen[b], Ld = dlen[b], so = soff[b], df = doff[b];
    switch (Ls) {
        case 32:  attn_body<32> (KT, QT, OT, Ps[w], N, so, df, Ld, h, lane); break;
        case 64:  attn_body<64> (KT, QT, OT, Ps[w], N, so, df, Ld, h, lane); break;
        case 96:  attn_body<96> (KT, QT, OT, Ps[w], N, so, df, Ld, h, lane); break;
        default:  attn_body<128>(KT, QT, OT, Ps[w], N, so, df, Ld, h, lane); break;
    }
}

// ---------------------------------------------------------------------------
// K3: GEMM1 (128x128, BK=32, depth-1 dbuf, XCD swizzle; R11 exact).
// ---------------------------------------------------------------------------
__global__ __launch_bounds__(256) void gemm1_mfma(
    const unsigned short* __restrict__ QT, const unsigned short* __restrict__ OT,
    const unsigned short* __restrict__ W, const float* __restrict__ bias,
    unsigned short* __restrict__ out, float* __restrict__ sum, float* __restrict__ sq,
    int N)
{
    __shared__ unsigned short Abuf[2][8 * 512];
    __shared__ unsigned short Bbuf[2][8 * 512];
    const int tid = threadIdx.x;
    const int w = tid >> 6, lane = tid & 63;
    // XCD swizzle decode: bid = 8*(2*(y/8)+cb) + (y%8)
    const int bid = blockIdx.x;
    const int xcd = bid & 7, q = bid >> 3;
    const int cb = q & 1, y = (q >> 1) * 8 + xcd;
    const int rowBase = y * 128, colBase = cb * 128;
    const int lr = lane & 15, lq = lane >> 4;
    const int wm = w >> 1, wn = w & 1;

    f32x4 acc[4][4];
    #pragma unroll
    for (int i = 0; i < 4; ++i)
        #pragma unroll
        for (int j = 0; j < 4; ++j) { f32x4 z = {0.f, 0.f, 0.f, 0.f}; acc[i][j] = z; }

    // K-step ks in [0,16): phase = ks>>3 (QT then OT), head hh = ks&7.
    auto stage = [&](int ks, int bi) {
        const unsigned short* __restrict__ Ap = (ks < 8) ? QT : OT;
        const int hh = ks & 7;
        #pragma unroll
        for (int s = 0; s < 2; ++s) {
            const int sub = 2 * w + s;
            gl_lds16(Ap + (size_t)(hh * N + rowBase + sub * 16 + lr) * 32 + lq * 8,
                     &Abuf[bi][sub * 512]);
            gl_lds16(W + (size_t)(colBase + sub * 16 + lr) * 512 + ks * 32 + lq * 8,
                     &Bbuf[bi][sub * 512]);
        }
    };
    auto compute = [&](int bi) {
        bf16x8 af[4], bfr[4];
        #pragma unroll
        for (int i = 0; i < 4; ++i) af[i] = *(const bf16x8*)&Abuf[bi][(wm * 4 + i) * 512 + lane * 8];
        #pragma unroll
        for (int j = 0; j < 4; ++j) bfr[j] = *(const bf16x8*)&Bbuf[bi][(wn * 4 + j) * 512 + lane * 8];
        #pragma unroll
        for (int i = 0; i < 4; ++i)
            #pragma unroll
            for (int j = 0; j < 4; ++j)
                acc[i][j] = __builtin_amdgcn_mfma_f32_16x16x32_bf16(af[i], bfr[j], acc[i][j], 0, 0, 0);
    };

    stage(0, 0);
    __syncthreads();
    for (int ks = 0; ks < 16; ks += 2) {
        stage(ks + 1, 1);
        compute(0);
        __syncthreads();
        if (ks + 2 < 16) stage(ks + 2, 0);
        compute(1);
        __syncthreads();
    }

    const int col0 = colBase + wn * 64;
    #pragma unroll
    for (int j = 0; j < 4; ++j) {
        const int col = col0 + j * 16 + lr;
        const float bv = bias[col];
        float cs = 0.f, cq = 0.f;
        #pragma unroll
        for (int i = 0; i < 4; ++i) {
            const int row0 = rowBase + wm * 64 + i * 16 + lq * 4;
            #pragma unroll
            for (int r = 0; r < 4; ++r) {
                const float v = acc[i][j][r] + bv;
                cs += v; cq += v * v;
                out[(size_t)(row0 + r) * 256 + col] = f2bf(v);
            }
        }
        cs += __shfl_xor(cs, 16); cs += __shfl_xor(cs, 32);
        cq += __shfl_xor(cq, 16); cq += __shfl_xor(cq, 32);
        if (lq == 0) { atomicAdd(&sum[col], cs); atomicAdd(&sq[col], cq); }
    }
}

// ---------------------------------------------------------------------------
// K5: GEMM2 with FUSED bn1+relu on the A path + XCD swizzle (R11 exact).
// ---------------------------------------------------------------------------
__global__ __launch_bounds__(256) void gemm2_fused(
    const unsigned short* __restrict__ y1,
    const unsigned short* __restrict__ W, const float* __restrict__ bias,
    const float* __restrict__ sum1, const float* __restrict__ sq1,
    const float* __restrict__ gamma1, const float* __restrict__ beta1,
    unsigned short* __restrict__ out, float* __restrict__ sum, float* __restrict__ sq,
    float invN)
{
    __shared__ unsigned short Abuf[2][8 * 512];
    __shared__ unsigned short Bbuf[2][8 * 512];
    __shared__ float scs[256], shs[256];
    const int tid = threadIdx.x;
    const int w = tid >> 6, lane = tid & 63;
    const int bid = blockIdx.x;
    const int xcd = bid & 7, q = bid >> 3;
    const int cb = q & 1, y = (q >> 1) * 8 + xcd;
    const int rowBase = y * 128, colBase = cb * 128;
    const int lr = lane & 15, lq = lane >> 4;
    const int wm = w >> 1, wn = w & 1;

    {   // per-column bn1 scale/shift (identical arithmetic to bnrelu)
        const float mean = sum1[tid] * invN;
        const float var  = sq1[tid] * invN - mean * mean;
        const float rstd = rsqrtf(var + 1e-5f);
        const float sc = gamma1[tid] * rstd;
        scs[tid] = sc;
        shs[tid] = beta1[tid] - mean * sc;
    }

    f32x4 acc[4][4];
    #pragma unroll
    for (int i = 0; i < 4; ++i)
        #pragma unroll
        for (int j = 0; j < 4; ++j) { f32x4 z = {0.f, 0.f, 0.f, 0.f}; acc[i][j] = z; }

    bf16x8 rawA[2];
    auto loadA = [&](int ks) {
        #pragma unroll
        for (int s = 0; s < 2; ++s) {
            const int sub = 2 * w + s;
            rawA[s] = *(const bf16x8*)&y1[(size_t)(rowBase + sub * 16 + lr) * 256 + ks * 32 + lq * 8];
        }
    };
    auto writeA = [&](int ks, int bi) {
        const int k0 = ks * 32 + lq * 8;
        #pragma unroll
        for (int s = 0; s < 2; ++s) {
            const int sub = 2 * w + s;
            bf16x8 o;
            #pragma unroll
            for (int j = 0; j < 8; ++j)
                o[j] = (short)f2bf(fmaxf(bfe2f(rawA[s][j]) * scs[k0 + j] + shs[k0 + j], 0.f));
            *(bf16x8*)&Abuf[bi][sub * 512 + lane * 8] = o;
        }
    };
    auto stageB = [&](int ks, int bi) {
        #pragma unroll
        for (int s = 0; s < 2; ++s) {
            const int sub = 2 * w + s;
            gl_lds16(W + (size_t)(colBase + sub * 16 + lr) * 256 + ks * 32 + lq * 8,
                     &Bbuf[bi][sub * 512]);
        }
    };
    auto compute = [&](int bi) {
        bf16x8 af[4], bfr[4];
        #pragma unroll
        for (int i = 0; i < 4; ++i) af[i] = *(const bf16x8*)&Abuf[bi][(wm * 4 + i) * 512 + lane * 8];
        #pragma unroll
        for (int j = 0; j < 4; ++j) bfr[j] = *(const bf16x8*)&Bbuf[bi][(wn * 4 + j) * 512 + lane * 8];
        #pragma unroll
        for (int i = 0; i < 4; ++i)
            #pragma unroll
            for (int j = 0; j < 4; ++j)
                acc[i][j] = __builtin_amdgcn_mfma_f32_16x16x32_bf16(af[i], bfr[j], acc[i][j], 0, 0, 0);
    };

    __syncthreads();                     // scs/shs visible
    loadA(0); stageB(0, 0); writeA(0, 0);
    __syncthreads();                     // Abuf[0] written, Bbuf[0] landed
    for (int ks = 0; ks < 8; ++ks) {
        const int cur = ks & 1;
        if (ks + 1 < 8) { loadA(ks + 1); stageB(ks + 1, cur ^ 1); }
        compute(cur);
        if (ks + 1 < 8) writeA(ks + 1, cur ^ 1);
        __syncthreads();
    }

    const int col0 = colBase + wn * 64;
    #pragma unroll
    for (int j = 0; j < 4; ++j) {
        const int col = col0 + j * 16 + lr;
        const float bv = bias[col];
        float cs = 0.f, cq = 0.f;
        #pragma unroll
        for (int i = 0; i < 4; ++i) {
            const int row0 = rowBase + wm * 64 + i * 16 + lq * 4;
            #pragma unroll
            for (int r = 0; r < 4; ++r) {
                const float v = acc[i][j][r] + bv;
                cs += v; cq += v * v;
                out[(size_t)(row0 + r) * 256 + col] = f2bf(v);
            }
        }
        cs += __shfl_xor(cs, 16); cs += __shfl_xor(cs, 32);
        cq += __shfl_xor(cq, 16); cq += __shfl_xor(cq, 32);
        if (lq == 0) { atomicAdd(&sum[col], cs); atomicAdd(&sq[col], cq); }
    }
}

// ---------------------------------------------------------------------------
// epilogue: out = dst + bn2(y2bf), finalize inlined. 8 elems/thread.
// ---------------------------------------------------------------------------
__global__ __launch_bounds__(256) void epilogue_kernel(
    const float* __restrict__ dst, const unsigned short* __restrict__ y2,
    const float* __restrict__ sum, const float* __restrict__ sq,
    const float* __restrict__ gamma, const float* __restrict__ beta,
    float* __restrict__ out, int n8, float invN)
{
    const int i = blockIdx.x * 256 + threadIdx.x;
    if (i >= n8) return;
    const int j0 = (i & 31) * 8;
    const bf16x8 yv = ((const bf16x8*)y2)[i];
    const float4 d0 = ((const float4*)dst)[2 * i];
    const float4 d1 = ((const float4*)dst)[2 * i + 1];
    float o[8];
    const float dv[8] = {d0.x, d0.y, d0.z, d0.w, d1.x, d1.y, d1.z, d1.w};
    #pragma unroll
    for (int j = 0; j < 8; ++j) {
        const float mean = sum[j0 + j] * invN;
        const float var  = sq[j0 + j] * invN - mean * mean;
        const float rstd = rsqrtf(var + 1e-5f);
        const float sc = gamma[j0 + j] * rstd;
        const float sh = beta[j0 + j] - mean * sc;
        o[j] = dv[j] + bfe2f(yv[j]) * sc + sh;
    }
    float4 o0, o1;
    o0.x = o[0]; o0.y = o[1]; o0.z = o[2]; o0.w = o[3];
    o1.x = o[4]; o1.y = o[5]; o1.z = o[6]; o1.w = o[7];
    ((float4*)out)[2 * i]     = o0;
    ((float4*)out)[2 * i + 1] = o1;
}

// ---------------------------------------------------------------------------
extern "C" void kernel_launch(void* const* d_in, const int* in_sizes, int n_in,
                              void* d_out, int out_size, void* d_ws, size_t ws_size,
                              hipStream_t stream)
{
    const float* src_h  = (const float*)d_in[0];
    const float* dst_h  = (const float*)d_in[1];
    const int*   slen   = (const int*)d_in[2];
    const int*   dlen   = (const int*)d_in[3];
    const float* W1     = (const float*)d_in[4];
    const float* b1     = (const float*)d_in[5];
    const float* gamma1 = (const float*)d_in[6];
    const float* beta1  = (const float*)d_in[7];
    const float* W2     = (const float*)d_in[8];
    const float* b2     = (const float*)d_in[9];
    const float* gamma2 = (const float*)d_in[10];
    const float* beta2  = (const float*)d_in[11];
    float* out = (float*)d_out;

    const int N = in_sizes[1] / H;     // 40960
    const int B = in_sizes[2];         // 512

    // ---- workspace layout (bytes) ----
    char* base = (char*)d_ws;
    int*   soff   = (int*)(base + 0);            // 2KB
    int*   doff   = (int*)(base + 2048);         // 2KB
    float* stats  = (float*)(base + 4096);       // 4KB: sum1, sq1, sum2, sq2
    unsigned short* W1p  = (unsigned short*)(base + 16384);            // 256KB
    unsigned short* W2bf = (unsigned short*)(base + 16384 + 262144);   // 128KB
    const size_t S = (size_t)N * H * sizeof(unsigned short);           // 21 MB
    char* big = base + (1 << 20);
    unsigned short* KT  = (unsigned short*)(big);
    // big + S: former VT2 slot, now unused
    unsigned short* QT  = (unsigned short*)(big + 2 * S);
    unsigned short* OT  = (unsigned short*)(big + 3 * S);
    unsigned short* y1bf = KT;    // reuse after attention
    unsigned short* y2bf = QT;    // reuse after gemm1 (gemm2 reads y1bf only)

    const float invN = 1.0f / (float)N;

    const int prepB = N >> 5;                       // 1280
    pre_kernel<<<prepB + 768 + 1, 256, 0, stream>>>(
        src_h, dst_h, W1, W2, slen, dlen,
        KT, QT, W1p, W2bf, soff, doff, stats, N, B);

    attn_mfma<<<B * 2, 256, 0, stream>>>(KT, QT, OT, soff, doff, slen, dlen, N);

    // 640 blocks = 320 row panels x 2 col blocks, XCD-paired
    gemm1_mfma<<<640, 256, 0, stream>>>(QT, OT, W1p, b1, y1bf, stats + 0, stats + 256, N);

    gemm2_fused<<<640, 256, 0, stream>>>(
        y1bf, W2bf, b2, stats + 0, stats + 256, gamma1, beta1,
        y2bf, stats + 512, stats + 768, invN);

    const int n8 = N * H / 8;
    epilogue_kernel<<<(n8 + 255) / 256, 256, 0, stream>>>(
        dst_h, y2bf, stats + 512, stats + 768, gamma2, beta2, out, n8, invN);
}